// Round 8
// baseline (778.508 us; speedup 1.0000x reference)
//
#include <hip/hip_runtime.h>
#include <cstdint>
#include <cstddef>

#define NN 50000
#define EE 1000000
#define NBK 196          // dst buckets (dst>>8), 196*256 = 50176 >= NN
#define PW_EC 6144       // persistent waves, edgeconv (1536 blocks * 4; 6 blocks/CU LDS cap)
#define PW_AG 8192       // persistent waves, agg/sage2 (2048 blocks * 4)

typedef __attribute__((ext_vector_type(8))) short bf16x8;
typedef __attribute__((ext_vector_type(4))) short s16x4;
typedef __attribute__((ext_vector_type(4))) float f32x4;
typedef _Float16 f16;
typedef __attribute__((ext_vector_type(2))) _Float16 f16x2;
typedef __attribute__((ext_vector_type(4))) _Float16 f16x4;
typedef __attribute__((ext_vector_type(8))) _Float16 f16x8;

// truncation split: v == bf16(hi) + ~bf16(lo), residual ~2^-16 rel
__device__ __forceinline__ void split2(float v, short& hi, short& lo) {
    union { float f; unsigned int u; } a; a.f = v;
    unsigned short h16 = (unsigned short)(a.u >> 16);
    union { unsigned int u; float f; } hf; hf.u = ((unsigned int)h16) << 16;
    union { float f; unsigned int u; } b; b.f = v - hf.f;
    hi = (short)h16;
    lo = (short)(b.u >> 16);
}

// relu(p+q) in packed f16 (v_pk_add_f16 + v_pk_max_f16)
__device__ __forceinline__ f16x8 relupq(f16x8 p, f16x8 q) {
    f16x8 s = p + q;
    f16x8 z = {};
#if __has_builtin(__builtin_elementwise_max)
    return __builtin_elementwise_max(s, z);
#else
    f16x8 r;
#pragma unroll
    for (int j = 0; j < 8; j++) r[j] = (s[j] > (f16)0.f) ? s[j] : (f16)0.f;
    return r;
#endif
}

// ---------- workspace layout (byte offsets) ----------
#define OFF_WHL    ((size_t)0)          // 2*1024*64 bf16 = 262144
#define OFF_WSPP   ((size_t)262144)     // 64*4 f32
#define OFF_BIAS01 ((size_t)263168)     // 64 f32
#define OFF_W1PQT  ((size_t)263424)     // 3*64*128 f32
#define OFF_BIASPQ ((size_t)361728)     // 3*128 f32
#define OFF_WSAGET ((size_t)363264)     // 128*64 f32
#define OFF_BIAS21 ((size_t)396032)     // 64 f32
#define OFF_BNF    ((size_t)396288)     // 3*192 f32 (+pad to 2560)
#define OFF_W2BF   ((size_t)398848)     // 3*64*64 f16 = 24576
#define OFF_INVC4  ((size_t)423424)     // N*4 f32 = 800000 {ic1,ic2,ic3,0}
#define OFF_PZ4    ((size_t)1223424)    // N*4 f32 = 800000 {p1,p2,p3,zsum}
#define OFF_RP     ((size_t)2023424)    // (NN+1) i32 (+pad 200064)
#define OFF_PARTS  ((size_t)2223488)    // 256 i32 (+pad 4096)
#define OFF_DEG    ((size_t)2227584)    // N i32 (+pad 200064)
#define OFF_CNT01  ((size_t)2427648)    // N u32 (+pad 200064)  {c0 | c1<<16}
#define OFF_GHEAD  ((size_t)2627712)    // NBK i32 (+pad 4096)
#define OFF_SORT   ((size_t)2631808)    // E i32 = 4000000 (src | attr<<16), attr-sorted within node
#define OFF_H      ((size_t)6631808)    // N*64 f32 = 12800000
#define OFF_PI     ((size_t)19431808)   // N*192 f16 = 19200000 (P, interleaved 3 branches)
#define OFF_QI     ((size_t)38631808)   // N*192 f16 = 19200000 (Q, interleaved)
#define OFF_Y1I    ((size_t)57831808)   // N*192 f16 = 19200000 (end 77031808)
#define OFF_EBUCK  OFF_H                // overlay: E u32, dead before k_h
#define OFF_AGGI   OFF_PI               // overlay: N*192 f16, Pi dead after edgeconv

// ---------- K1: weight prep / folding ----------
__global__ __launch_bounds__(256) void k_prep(
    const float* __restrict__ Wspf, const float* __restrict__ bspf,
    const float* __restrict__ W011, const float* __restrict__ b011,
    const float* __restrict__ W012, const float* __restrict__ b012,
    const float* __restrict__ bn01,
    const float* __restrict__ e1W1, const float* __restrict__ e1b1,
    const float* __restrict__ e1b2, const float* __restrict__ bn11,
    const float* __restrict__ e2W1, const float* __restrict__ e2b1,
    const float* __restrict__ e2b2, const float* __restrict__ bn12,
    const float* __restrict__ e3W1, const float* __restrict__ e3b1,
    const float* __restrict__ e3b2, const float* __restrict__ bn13,
    const float* __restrict__ e1W2, const float* __restrict__ e2W2,
    const float* __restrict__ e3W2,
    const float* __restrict__ s21Wl, const float* __restrict__ s21bl,
    const float* __restrict__ s21Wr, const float* __restrict__ bn21,
    unsigned short* __restrict__ Whl, float* __restrict__ WspP, float* __restrict__ bias01,
    float* __restrict__ W1pqT, float* __restrict__ biasPQ,
    float* __restrict__ WsageT, float* __restrict__ bias21, float* __restrict__ bnf,
    f16* __restrict__ W2h)
{
    int idx = blockIdx.x * 256 + threadIdx.x;
    if (idx < 131072) {
        int hl = idx >> 16;
        int r = idx & 65535;
        int kchunk = r >> 11;
        int r2 = r & 2047;
        int blk = r2 >> 9;
        int r3 = r2 & 511;
        int lane = r3 >> 3;
        int j = r3 & 7;
        int n = lane & 15, quad = lane >> 4;
        int k = kchunk * 32 + quad * 8 + j;
        int c = blk * 16 + n;
        float s = bn01[c] * rsqrtf(bn01[192 + c] + 1e-5f);
        float w = ((k < 512) ? W012[c * 512 + k] : W011[c * 576 + (k - 512)]) * s;
        short hi, lo;
        split2(w, hi, lo);
        Whl[idx] = (unsigned short)(hl ? lo : hi);
    } else if (idx < 131072 + 24576) {
        int r = idx - 131072;
        int b = r >> 13; r &= 8191;
        int k = r >> 7, cp = r & 127;
        const float* W1 = (b == 0) ? e1W1 : (b == 1) ? e2W1 : e3W1;
        float val;
        if (cp < 64) val = W1[cp * 128 + k] - W1[cp * 128 + 64 + k];
        else         val = W1[(cp - 64) * 128 + 64 + k];
        W1pqT[b * 8192 + k * 128 + cp] = val;
    } else if (idx < 131072 + 24576 + 8192) {
        int r = idx - (131072 + 24576);
        int k = r >> 6, c = r & 63;
        float s = bn21[c] * rsqrtf(bn21[192 + c] + 1e-5f);
        float w = (k < 64) ? s21Wl[c * 64 + k] : s21Wr[c * 64 + (k - 64)];
        WsageT[k * 64 + c] = w * s;
    } else if (idx < 131072 + 24576 + 8192 + 64) {
        int c = idx - (131072 + 24576 + 8192);
        float s01 = bn01[c] * rsqrtf(bn01[192 + c] + 1e-5f);
        float wsp0 = 0.f, wsp1 = 0.f, wsp2 = 0.f, wsp3 = 0.f, bacc = 0.f;
        for (int j = 0; j < 64; j++) {
            float w = W011[c * 576 + 512 + j];
            wsp0 += w * Wspf[j * 4 + 0];
            wsp1 += w * Wspf[j * 4 + 1];
            wsp2 += w * Wspf[j * 4 + 2];
            wsp3 += w * Wspf[j * 4 + 3];
            bacc += w * bspf[j];
        }
        WspP[c * 4 + 0] = wsp0 * s01; WspP[c * 4 + 1] = wsp1 * s01;
        WspP[c * 4 + 2] = wsp2 * s01; WspP[c * 4 + 3] = wsp3 * s01;
        bias01[c] = (b011[c] + b012[c] + bacc) * s01 + (bn01[64 + c] - bn01[128 + c] * s01);
        float s21 = bn21[c] * rsqrtf(bn21[192 + c] + 1e-5f);
        bias21[c] = s21bl[c] * s21 + (bn21[64 + c] - bn21[128 + c] * s21);
        const float* b1a[3] = { e1b1, e2b1, e3b1 };
        const float* b2a[3] = { e1b2, e2b2, e3b2 };
        const float* bna[3] = { bn11, bn12, bn13 };
#pragma unroll
        for (int b = 0; b < 3; b++) {
            float s = bna[b][c] * rsqrtf(bna[b][192 + c] + 1e-5f);
            float tr = bna[b][64 + c] - bna[b][128 + c] * s;
            bnf[b * 192 + c] = s;
            bnf[b * 192 + 64 + c] = b2a[b][c] * s + tr;
            bnf[b * 192 + 128 + c] = tr;
            biasPQ[b * 128 + c] = b1a[b][c];
            biasPQ[b * 128 + 64 + c] = 0.f;
        }
    } else if (idx < 131072 + 24576 + 8192 + 64 + 12288) {
        int r = idx - (131072 + 24576 + 8192 + 64);
        int b = r >> 12, i = r & 4095;
        const float* W2 = (b == 0) ? e1W2 : (b == 1) ? e2W2 : e3W2;
        W2h[b * 4096 + i] = (f16)W2[i];
    }
}

// ---------- degree histogram + per-class counts (c0=|a==0|, c1=|a==1|) ----------
__global__ __launch_bounds__(256) void k_hist(
    const int* __restrict__ dst, const int* __restrict__ attr,
    int* __restrict__ deg, unsigned int* __restrict__ cnt01)
{
    int e = blockIdx.x * 256 + threadIdx.x;
    if (e < EE) {
        int d = dst[e];
        int a = attr[e] + 1;            // 0,1,2
        atomicAdd(&deg[d], 1);
        if (a == 0)      atomicAdd(&cnt01[d], 1u);
        else if (a == 1) atomicAdd(&cnt01[d], 0x10000u);
    }
}

__global__ __launch_bounds__(256) void k_psum(const int* __restrict__ deg, int* __restrict__ parts)
{
    int i = blockIdx.x * 256 + threadIdx.x;
    int v = (i < NN) ? deg[i] : 0;
#pragma unroll
    for (int off = 32; off > 0; off >>= 1) v += __shfl_xor(v, off);
    __shared__ int ws4[4];
    int wid = threadIdx.x >> 6;
    if ((threadIdx.x & 63) == 0) ws4[wid] = v;
    __syncthreads();
    if (threadIdx.x == 0)
        parts[blockIdx.x] = ws4[0] + ws4[1] + ws4[2] + ws4[3];
}

// exclusive scan of bucket counts; also emits ghead (= bucket base = rp[b*256])
__global__ __launch_bounds__(256) void k_pscan(int* __restrict__ parts, int* __restrict__ ghead)
{
    __shared__ int sbuf[256];
    int tid = threadIdx.x;
    int v = (tid < NBK) ? parts[tid] : 0;
    sbuf[tid] = v;
    __syncthreads();
    for (int off = 1; off < 256; off <<= 1) {
        int t = (tid >= off) ? sbuf[tid - off] : 0;
        __syncthreads();
        sbuf[tid] += t;
        __syncthreads();
    }
    if (tid < NBK) {
        int ex = sbuf[tid] - v;
        parts[tid] = ex;
        ghead[tid] = ex;
    }
}

__global__ __launch_bounds__(256) void k_scanfix(
    const int* __restrict__ deg, const int* __restrict__ parts, int* __restrict__ rowptr)
{
    __shared__ int sbuf[256];
    int tid = threadIdx.x;
    int i = blockIdx.x * 256 + tid;
    int v = (i < NN) ? deg[i] : 0;
    sbuf[tid] = v;
    __syncthreads();
    for (int off = 1; off < 256; off <<= 1) {
        int t = (tid >= off) ? sbuf[tid - off] : 0;
        __syncthreads();
        sbuf[tid] += t;
        __syncthreads();
    }
    int base = parts[blockIdx.x];
    if (i < NN)      rowptr[i] = base + sbuf[tid] - v;
    if (i == NN - 1) rowptr[NN] = base + sbuf[tid];
}

// ---------- bucketed sort pass A: partition edges into dst-buckets ----------
__global__ __launch_bounds__(256) void k_bucketA(
    const int* __restrict__ src, const int* __restrict__ dst, const int* __restrict__ attr,
    int* __restrict__ ghead, unsigned int* __restrict__ ebuck)
{
    __shared__ int hist[NBK];
    __shared__ int head[NBK];
    int tid = threadIdx.x;
    if (tid < NBK) hist[tid] = 0;
    __syncthreads();
    int base_e = blockIdx.x * 4096;
    unsigned int word[16]; int bkt[16];
#pragma unroll
    for (int k = 0; k < 16; k++) {
        int e = base_e + k * 256 + tid;
        if (e < EE) {
            int d = dst[e], s = src[e], a = attr[e] + 1;
            int b = d >> 8;
            word[k] = (unsigned)s | ((unsigned)a << 16) | ((unsigned)(d & 255) << 18);
            bkt[k] = b;
            atomicAdd(&hist[b], 1);
        } else { bkt[k] = -1; word[k] = 0; }
    }
    __syncthreads();
    if (tid < NBK) {
        int c = hist[tid];
        head[tid] = c ? atomicAdd(&ghead[tid], c) : 0;
    }
    __syncthreads();
#pragma unroll
    for (int k = 0; k < 16; k++) {
        if (bkt[k] >= 0) {
            int pos = atomicAdd(&head[bkt[k]], 1);
            ebuck[pos] = word[k];
        }
    }
}

// ---------- bucketed sort pass B: sort by (dst&255, attr) within bucket (1024 bins) ----------
__global__ __launch_bounds__(256) void k_bucketB(
    const int* __restrict__ rp, const unsigned int* __restrict__ ebuck,
    int* __restrict__ sorted)
{
    __shared__ int sbuf[1024];
    __shared__ int head[1024];
    __shared__ int s2[256];
    int b = blockIdx.x, tid = threadIdx.x;
    int n0 = b * 256;
    int n1 = n0 + 256; if (n1 > NN) n1 = NN;
    int r0 = rp[n0];
    int r1 = rp[n1];
    for (int i = tid; i < 1024; i += 256) sbuf[i] = 0;
    __syncthreads();
    for (int e = r0 + tid; e < r1; e += 256)
        atomicAdd(&sbuf[(ebuck[e] >> 16) & 1023], 1);    // key = (d&255)*4 + a
    __syncthreads();
    int i0 = tid * 4;
    int v0 = sbuf[i0], v1 = sbuf[i0 + 1], v2 = sbuf[i0 + 2], v3 = sbuf[i0 + 3];
    int tot = v0 + v1 + v2 + v3;
    s2[tid] = tot;
    __syncthreads();
    for (int off = 1; off < 256; off <<= 1) {
        int t = (tid >= off) ? s2[tid - off] : 0;
        __syncthreads();
        s2[tid] += t;
        __syncthreads();
    }
    int ex = s2[tid] - tot;
    head[i0]     = r0 + ex;
    head[i0 + 1] = r0 + ex + v0;
    head[i0 + 2] = r0 + ex + v0 + v1;
    head[i0 + 3] = r0 + ex + v0 + v1 + v2;
    __syncthreads();
    for (int e = r0 + tid; e < r1; e += 256) {
        unsigned int w = ebuck[e];
        int pos = atomicAdd(&head[(w >> 16) & 1023], 1);
        sorted[pos] = (int)(w & 0x3FFFFu);   // src | attr<<16
    }
}

// ---------- K2: h = relu(fold_bn01(x @ Wc')) ----------
__global__ __launch_bounds__(256) void k_h(
    const float* __restrict__ x, const unsigned short* __restrict__ Whl,
    const float* __restrict__ WspP, const float* __restrict__ bias01,
    float* __restrict__ h)
{
    __shared__ unsigned short hib[2][4096];
    __shared__ unsigned short lob[2][4096];
    int tid = threadIdx.x;
    int w = tid >> 6, l = tid & 63;
    int tile = blockIdx.x;
    int m = l & 15, quad = l >> 4;
    int blk = w;
    const unsigned short* Wh = Whl;
    const unsigned short* Wl = Whl + 65536;
    const size_t xbase = (size_t)tile * 16 * 1028;

    int oct_w = l >> 1, off_w = (l & 1) * 4;

    f32x4 g[4];
#pragma unroll
    for (int p = 0; p < 4; p++)
        g[p] = *(const f32x4*)(x + xbase + (size_t)(p * 4 + w) * 1028 + l * 4);
#pragma unroll
    for (int p = 0; p < 4; p++) {
        int r = p * 4 + w;
        int op = r * 256 + (oct_w ^ (r & 7)) * 8 + off_w;
        s16x4 h4, l4;
#pragma unroll
        for (int i = 0; i < 4; i++) { short hi, lo; split2(g[p][i], hi, lo); h4[i] = hi; l4[i] = lo; }
        *(s16x4*)(&hib[0][op]) = h4;
        *(s16x4*)(&lob[0][op]) = l4;
    }
    __syncthreads();

    f32x4 acc = { 0.f, 0.f, 0.f, 0.f };
    for (int c = 0; c < 4; c++) {
        if (c < 3) {
#pragma unroll
            for (int p = 0; p < 4; p++)
                g[p] = *(const f32x4*)(x + xbase + (size_t)(p * 4 + w) * 1028 + (c + 1) * 256 + l * 4);
        }
        int buf = c & 1;
        const unsigned short* hp = &hib[buf][m * 256];
        const unsigned short* lp = &lob[buf][m * 256];
        int msw = m & 7;
#pragma unroll
        for (int ks = 0; ks < 8; ks++) {
            int oct = ks * 4 + quad;
            int ao = (oct ^ msw) * 8;
            bf16x8 xh = *(const bf16x8*)(hp + ao);
            bf16x8 xl = *(const bf16x8*)(lp + ao);
            int fb = (c * 8 + ks) * 2048 + blk * 512 + l * 8;
            bf16x8 bh = *(const bf16x8*)(Wh + fb);
            bf16x8 bl = *(const bf16x8*)(Wl + fb);
            acc = __builtin_amdgcn_mfma_f32_16x16x32_bf16(xh, bh, acc, 0, 0, 0);
            acc = __builtin_amdgcn_mfma_f32_16x16x32_bf16(xl, bh, acc, 0, 0, 0);
            acc = __builtin_amdgcn_mfma_f32_16x16x32_bf16(xh, bl, acc, 0, 0, 0);
        }
        if (c < 3) {
            int nbuf = (c + 1) & 1;
#pragma unroll
            for (int p = 0; p < 4; p++) {
                int r = p * 4 + w;
                int op = r * 256 + (oct_w ^ (r & 7)) * 8 + off_w;
                s16x4 h4, l4;
#pragma unroll
                for (int i = 0; i < 4; i++) { short hi, lo; split2(g[p][i], hi, lo); h4[i] = hi; l4[i] = lo; }
                *(s16x4*)(&hib[nbuf][op]) = h4;
                *(s16x4*)(&lob[nbuf][op]) = l4;
            }
            __syncthreads();
        }
    }

    int ch = blk * 16 + m;
    f32x4 wsp = *(const f32x4*)(WspP + ch * 4);
    float bia = bias01[ch];
#pragma unroll
    for (int r = 0; r < 4; r++) {
        int row = tile * 16 + quad * 4 + r;
        f32x4 sp = *(const f32x4*)(x + (size_t)row * 1028 + 1024);
        float a = acc[r] + sp[0] * wsp[0] + sp[1] * wsp[1]
                + sp[2] * wsp[2] + sp[3] * wsp[3] + bia;
        h[(size_t)row * 64 + ch] = fmaxf(a, 0.f);
    }
}

// ---------- K4: all 3 branches fused: P = h @ W1p' + b1 (f16), Q = h @ W1q' (f16) ----------
__global__ __launch_bounds__(256) void k_pq(
    const float* __restrict__ h, const float* __restrict__ WT3,
    const float* __restrict__ biasPQ, f16* __restrict__ Pi, f16* __restrict__ Qi)
{
    __shared__ float wt[64 * 128];
    __shared__ float xt[64 * 68];
    int tid = threadIdx.x;
    int m0 = blockIdx.x * 64;
    int cg = tid & 31, rg = tid >> 5;
#pragma unroll
    for (int i = 0; i < 4; i++) {
        int li = i * 256 + tid;
        int rr = li >> 4, q = li & 15;
        int row = m0 + rr;
        float4 u = make_float4(0.f, 0.f, 0.f, 0.f);
        if (row < NN) u = *(const float4*)(h + (size_t)row * 64 + q * 4);
        *(float4*)(xt + rr * 68 + q * 4) = u;
    }
    for (int b = 0; b < 3; b++) {
        __syncthreads();
#pragma unroll
        for (int i = 0; i < 8; i++)
            ((float4*)wt)[i * 256 + tid] = ((const float4*)(WT3 + b * 8192))[i * 256 + tid];
        __syncthreads();
        float acc[8][4];
#pragma unroll
        for (int r = 0; r < 8; r++)
#pragma unroll
            for (int j = 0; j < 4; j++) acc[r][j] = 0.f;
#pragma unroll 8
        for (int k = 0; k < 64; k++) {
            float4 wv = *(const float4*)(wt + k * 128 + cg * 4);
#pragma unroll
            for (int r = 0; r < 8; r++) {
                float xv = xt[(rg * 8 + r) * 68 + k];
                acc[r][0] += xv * wv.x; acc[r][1] += xv * wv.y;
                acc[r][2] += xv * wv.z; acc[r][3] += xv * wv.w;
            }
        }
        const float* biasP = biasPQ + b * 128;
#pragma unroll
        for (int r = 0; r < 8; r++) {
            int row = m0 + rg * 8 + r;
            if (row < NN) {
                if (cg < 16) {               // P half (+bias), fp16
                    f16x4 res;
#pragma unroll
                    for (int j = 0; j < 4; j++)
                        res[j] = (f16)(acc[r][j] + biasP[cg * 4 + j]);
                    *(f16x4*)(Pi + (size_t)row * 192 + b * 64 + cg * 4) = res;
                } else {                     // Q half, fp16
                    f16x4 res;
#pragma unroll
                    for (int j = 0; j < 4; j++)
                        res[j] = (f16)acc[r][j];
                    *(f16x4*)(Qi + (size_t)row * 192 + b * 64 + (cg - 16) * 4) = res;
                }
            }
        }
    }
}

// per-branch contiguous range: batches of 16, mask-free except tail row test.
#define ECV_BRANCH(B, EST, ECN)                                                    \
    {                                                                              \
        f16x8 pl = *(const f16x8*)(pr + (B) * 64 + quad * 8);                      \
        f16x8 ph = *(const f16x8*)(pr + (B) * 64 + 32 + quad * 8);                 \
        float acc[4][4];                                                           \
        _Pragma("unroll") for (int blk = 0; blk < 4; blk++)                        \
            _Pragma("unroll") for (int r = 0; r < 4; r++) acc[blk][r] = -3.0e38f;  \
        int nbF = (ECN) >> 4;                                                      \
        int rem = (ECN) & 15;                                                      \
        for (int bi = 0; bi < nbF; bi++) {                                         \
            int srcm = sorted[(EST) + bi * 16 + m] & 0xFFFF;                       \
            const f16* qr = Qi + (size_t)srcm * 192 + (B) * 64;                    \
            f16x8 q0 = *(const f16x8*)(qr + quad * 8);                             \
            f16x8 q1 = *(const f16x8*)(qr + 32 + quad * 8);                        \
            f16x8 a0 = relupq(pl, q0);                                             \
            f16x8 a1 = relupq(ph, q1);                                             \
            _Pragma("unroll") for (int blk = 0; blk < 4; blk++) {                  \
                f32x4 c = { 0.f, 0.f, 0.f, 0.f };                                  \
                f16x8 w0 = *(const f16x8*)(w2s + ((B) * 8 + blk * 2 + 0) * 512 + quad * 128 + m * 8); \
                f16x8 w1 = *(const f16x8*)(w2s + ((B) * 8 + blk * 2 + 1) * 512 + quad * 128 + m * 8); \
                c = __builtin_amdgcn_mfma_f32_16x16x32_f16(a0, w0, c, 0, 0, 0);    \
                c = __builtin_amdgcn_mfma_f32_16x16x32_f16(a1, w1, c, 0, 0, 0);    \
                _Pragma("unroll") for (int r = 0; r < 4; r++)                      \
                    acc[blk][r] = fmaxf(acc[blk][r], c[r]);                        \
            }                                                                      \
        }                                                                          \
        if (rem) {                                                                 \
            int e = (EST) + nbF * 16 + m;                                          \
            int srcm = sorted[(m < rem) ? e : (EST)] & 0xFFFF;                     \
            const f16* qr = Qi + (size_t)srcm * 192 + (B) * 64;                    \
            f16x8 q0 = *(const f16x8*)(qr + quad * 8);                             \
            f16x8 q1 = *(const f16x8*)(qr + 32 + quad * 8);                        \
            f16x8 a0 = relupq(pl, q0);                                             \
            f16x8 a1 = relupq(ph, q1);                                             \
            _Pragma("unroll") for (int blk = 0; blk < 4; blk++) {                  \
                f32x4 c = { 0.f, 0.f, 0.f, 0.f };                                  \
                f16x8 w0 = *(const f16x8*)(w2s + ((B) * 8 + blk * 2 + 0) * 512 + quad * 128 + m * 8); \
                f16x8 w1 = *(const f16x8*)(w2s + ((B) * 8 + blk * 2 + 1) * 512 + quad * 128 + m * 8); \
                c = __builtin_amdgcn_mfma_f32_16x16x32_f16(a0, w0, c, 0, 0, 0);    \
                c = __builtin_amdgcn_mfma_f32_16x16x32_f16(a1, w1, c, 0, 0, 0);    \
                _Pragma("unroll") for (int r = 0; r < 4; r++)                      \
                    if (quad * 4 + r < rem)                                        \
                        acc[blk][r] = fmaxf(acc[blk][r], c[r]);                    \
            }                                                                      \
        }                                                                          \
        float red[4];                                                              \
        _Pragma("unroll") for (int blk = 0; blk < 4; blk++) {                      \
            float rv = fmaxf(fmaxf(acc[blk][0], acc[blk][1]),                      \
                             fmaxf(acc[blk][2], acc[blk][3]));                     \
            rv = fmaxf(rv, __shfl_xor(rv, 16));                                    \
            rv = fmaxf(rv, __shfl_xor(rv, 32));                                    \
            red[blk] = rv;                                                         \
        }                                                                          \
        float mx = red[quad];                                                      \
        const float* scb = bnf + (B) * 192;                                        \
        float outv = ((ECN) > 0) ? fmaxf(fmaf(mx, scb[lane], scb[64 + lane]), 0.f) \
                                 : fmaxf(scb[128 + lane], 0.f);                    \
        y1i[(size_t)v * 192 + (B) * 64 + lane] = (f16)outv;                        \
    }

// ---------- K5: fused 3-branch EdgeConv; attr-sorted ranges; persistent waves ----------
__global__ __launch_bounds__(256) void k_edgeconv_f(
    const int* __restrict__ rowptr, const unsigned int* __restrict__ cnt01,
    const int* __restrict__ sorted,
    const f16* __restrict__ Pi, const f16* __restrict__ Qi,
    const f16* __restrict__ W2h,               // 3*64*64 f16
    const float* __restrict__ bnf,             // 3*192
    f16* __restrict__ y1i, float* __restrict__ invc4)
{
    __shared__ f16 w2s[12288];                 // 3 branches : 24 frags * 512 halves, bank-permuted
    int tid = threadIdx.x;
#pragma unroll
    for (int u0 = 0; u0 < 6; u0++) {
        int u = u0 * 256 + tid;                // 0..1535
        int frag = u >> 6;                     // b*8 + blk*2 + kc   (b in {0,1,2})
        int rem = u & 63;
        int m2 = rem >> 2, qd = rem & 3;
        int bb = frag >> 3, blk = (frag >> 1) & 3, kc = frag & 1;
        *(int4*)(w2s + frag * 512 + qd * 128 + m2 * 8) =
            *(const int4*)(W2h + (bb * 64 + blk * 16 + m2) * 64 + kc * 32 + qd * 8);
    }
    __syncthreads();

    int wid = tid >> 6, lane = tid & 63;
    int m = lane & 15, quad = lane >> 4;
    int gw = blockIdx.x * 4 + wid;             // persistent wave id, PW_EC total

    for (int v = gw; v < NN; v += PW_EC) {
        const f16* pr = Pi + (size_t)v * 192;
        int e0 = rowptr[v], e1 = rowptr[v + 1];
        int deg = e1 - e0;
        unsigned int cc = cnt01[v];
        int c0 = (int)(cc & 0xFFFFu);
        int c1 = (int)(cc >> 16);
        int n1cnt = deg - c0;                  // seg1 (a>=1): [e0+c0, e1)
        int n2cnt = c0 + c1;                   // seg2 (a<=1): [e0, e0+c0+c1)

        ECV_BRANCH(0, e0 + c0, n1cnt)
        ECV_BRANCH(1, e0, n2cnt)
        ECV_BRANCH(2, e0, deg)

        if (lane == 0) {
            float4 ic;
            ic.x = 1.f / (float)(n1cnt > 0 ? n1cnt : 1);
            ic.y = 1.f / (float)(n2cnt > 0 ? n2cnt : 1);
            ic.z = 1.f / (float)(deg   > 0 ? deg   : 1);
            ic.w = 0.f;
            *(float4*)(invc4 + (size_t)v * 4) = ic;
        }
    }
}

// per-branch range mean: 8 lanes/edge, unconditional f16x8 loads
#define AGG_BRANCH(B, EST, ECN, ICS)                                               \
    {                                                                              \
        float s[8];                                                                \
        _Pragma("unroll") for (int j = 0; j < 8; j++) s[j] = 0.f;                  \
        for (int eb = 0; eb < (ECN); eb += 8) {                                    \
            if (eb + eslot < (ECN)) {                                              \
                int src = sorted[(EST) + eb + eslot] & 0xFFFF;                     \
                f16x8 u = *(const f16x8*)(y1i + (size_t)src * 192 + (B) * 64 + cg * 8); \
                _Pragma("unroll") for (int j = 0; j < 8; j++) s[j] += (float)u[j]; \
            }                                                                      \
        }                                                                          \
        _Pragma("unroll") for (int j = 0; j < 8; j++) {                            \
            s[j] += __shfl_xor(s[j], 8);                                           \
            s[j] += __shfl_xor(s[j], 16);                                          \
            s[j] += __shfl_xor(s[j], 32);                                          \
        }                                                                          \
        if (eslot == 0) {                                                          \
            f16x8 r;                                                               \
            _Pragma("unroll") for (int j = 0; j < 8; j++) r[j] = (f16)(s[j] * (ICS)); \
            *(f16x8*)(aggi + (size_t)v * 192 + (B) * 64 + cg * 8) = r;             \
        }                                                                          \
    }

// ---------- K6a: fused 3-branch mean aggregation; attr-sorted ranges ----------
__global__ __launch_bounds__(256) void k_agg_f(
    const int* __restrict__ rowptr, const unsigned int* __restrict__ cnt01,
    const int* __restrict__ sorted,
    const f16* __restrict__ y1i, const float* __restrict__ invc4,
    f16* __restrict__ aggi)
{
    int wid = threadIdx.x >> 6, lane = threadIdx.x & 63;
    int eslot = lane >> 3, cg = lane & 7;
    int gw = blockIdx.x * 4 + wid;
    for (int v = gw; v < NN; v += PW_AG) {
        int e0 = rowptr[v], e1 = rowptr[v + 1];
        int deg = e1 - e0;
        unsigned int cc = cnt01[v];
        int c0 = (int)(cc & 0xFFFFu);
        int c1 = (int)(cc >> 16);
        float4 icv = *(const float4*)(invc4 + (size_t)v * 4);
        AGG_BRANCH(0, e0 + c0, deg - c0, icv.x)
        AGG_BRANCH(1, e0, c0 + c1, icv.y)
        AGG_BRANCH(2, e0, deg, icv.z)
    }
}

// ---------- K6b: sage1 + fused proj, all 3 branches in one kernel ----------
__global__ __launch_bounds__(256) void k_sage1(
    const f16* __restrict__ aggi, const f16* __restrict__ y1i,
    const float* __restrict__ WsageT, const float* __restrict__ bias21,
    const float* __restrict__ Wl0, const float* __restrict__ bl0, const float* __restrict__ Wr0,
    const float* __restrict__ Wl1, const float* __restrict__ bl1, const float* __restrict__ Wr1,
    const float* __restrict__ Wl2, const float* __restrict__ bl2, const float* __restrict__ Wr2,
    float* __restrict__ pz4)
{
    __shared__ float wt[64 * 64];
    __shared__ float xt[128 * 68];
    __shared__ float wl[64], wr[64];
    int tid = threadIdx.x;
    int m0 = blockIdx.x * 128;
    int cg = tid & 15, rg = tid >> 4;
    float zsum[8];
#pragma unroll
    for (int r = 0; r < 8; r++) zsum[r] = 0.f;

    for (int b = 0; b < 3; b++) {
        const float* Wl3 = (b == 0) ? Wl0 : (b == 1) ? Wl1 : Wl2;
        const float* bl3 = (b == 0) ? bl0 : (b == 1) ? bl1 : bl2;
        const float* Wr3 = (b == 0) ? Wr0 : (b == 1) ? Wr1 : Wr2;
        __syncthreads();                     // guard wl/wr overwrite vs prior epilogue reads
        if (tid < 64) { wl[tid] = Wl3[tid]; wr[tid] = Wr3[tid]; }
        float blv = bl3[0];
        float acc[8][4];
#pragma unroll
        for (int r = 0; r < 8; r++)
#pragma unroll
            for (int j = 0; j < 4; j++) acc[r][j] = 0.f;
        for (int ch = 0; ch < 2; ch++) {
            const f16* A = (ch ? y1i : aggi) + b * 64;
            __syncthreads();
#pragma unroll
            for (int i = 0; i < 4; i++)
                ((float4*)wt)[i * 256 + tid] = ((const float4*)(WsageT + ch * 4096))[i * 256 + tid];
#pragma unroll
            for (int i = 0; i < 4; i++) {
                int li = i * 256 + tid;
                int rr = li >> 3, q = li & 7;
                int row = m0 + rr;
                f16x8 u = {};
                if (row < NN) u = *(const f16x8*)(A + (size_t)row * 192 + q * 8);
                float4 lo4 = make_float4((float)u[0], (float)u[1], (float)u[2], (float)u[3]);
                float4 hi4 = make_float4((float)u[4], (float)u[5], (float)u[6], (float)u[7]);
                *(float4*)(xt + rr * 68 + q * 8) = lo4;
                *(float4*)(xt + rr * 68 + q * 8 + 4) = hi4;
            }
            __syncthreads();
#pragma unroll 8
            for (int k = 0; k < 64; k++) {
                float4 wv = *(const float4*)(wt + k * 64 + cg * 4);
#pragma unroll
                for (int r = 0; r < 8; r++) {
                    float xv = xt[(rg * 8 + r) * 68 + k];
                    acc[r][0] += xv * wv.x; acc[r][1] += xv * wv.y;
                    acc[r][2] += xv * wv.z; acc[r][3] += xv * wv.w;
                }
            }
        }
#pragma unroll
        for (int r = 0; r < 8; r++) {
            int row = m0 + rg * 8 + r;
            float ap = 0.f, az = 0.f;
#pragma unroll
            for (int j = 0; j < 4; j++) {
                float t = fmaxf(acc[r][j] + bias21[cg * 4 + j], 0.f);
                ap += t * wl[cg * 4 + j];
                az += t * wr[cg * 4 + j];
            }
            ap += __shfl_xor(ap, 1); ap += __shfl_xor(ap, 2);
            ap += __shfl_xor(ap, 4); ap += __shfl_xor(ap, 8);
            az += __shfl_xor(az, 1); az += __shfl_xor(az, 2);
            az += __shfl_xor(az, 4); az += __shfl_xor(az, 8);
            zsum[r] += az + blv;
            if (cg == 0 && row < NN)
                pz4[(size_t)row * 4 + b] = ap;
        }
    }
#pragma unroll
    for (int r = 0; r < 8; r++) {
        int row = m0 + rg * 8 + r;
        if (cg == 0 && row < NN)
            pz4[(size_t)row * 4 + 3] = zsum[r];
    }
}

// ---------- K8: fused 3-branch sage2 + sigmoid; persistent waves ----------
__global__ __launch_bounds__(256) void k_sage2_f(
    const int* __restrict__ rowptr, const int* __restrict__ sorted,
    const float* __restrict__ pz4, const float* __restrict__ invc4,
    float* __restrict__ outp)
{
    int wid = threadIdx.x >> 6, lane = threadIdx.x & 63;
    int gw = blockIdx.x * 4 + wid;
    for (int v = gw; v < NN; v += PW_AG) {
        int e0 = rowptr[v], e1 = rowptr[v + 1];
        float s1 = 0.f, s2 = 0.f, s3 = 0.f;
        for (int e = e0 + lane; e < e1; e += 64) {
            int w = sorted[e];
            int src = w & 0xFFFF, a = (w >> 16) & 3;
            float4 pz = *(const float4*)(pz4 + (size_t)src * 4);
            s3 += pz.z;
            if (a >= 1) s1 += pz.x;
            if (a <= 1) s2 += pz.y;
        }
#pragma unroll
        for (int off = 32; off > 0; off >>= 1) {
            s1 += __shfl_xor(s1, off);
            s2 += __shfl_xor(s2, off);
            s3 += __shfl_xor(s3, off);
        }
        if (lane == 0) {
            float4 icv = *(const float4*)(invc4 + (size_t)v * 4);
            float zsum = pz4[(size_t)v * 4 + 3];
            float val = s1 * icv.x + s2 * icv.y + s3 * icv.z + zsum;
            outp[v] = 1.f / (1.f + expf(-val));
        }
    }
}

// ---------- launch ----------
extern "C" void kernel_launch(void* const* d_in, const int* in_sizes, int n_in,
                              void* d_out, int out_size, void* d_ws, size_t ws_size,
                              hipStream_t stream)
{
    const float* x    = (const float*)d_in[0];
    const int* ei     = (const int*)d_in[1];
    const int* attr   = (const int*)d_in[2];
    const float* Wspf = (const float*)d_in[3];
    const float* bspf = (const float*)d_in[4];
    const float* W011 = (const float*)d_in[5];
    const float* b011 = (const float*)d_in[6];
    const float* W012 = (const float*)d_in[7];
    const float* b012 = (const float*)d_in[8];
    const float* bn01 = (const float*)d_in[9];
    const float* eW1[3] = { (const float*)d_in[10], (const float*)d_in[15], (const float*)d_in[20] };
    const float* eb1[3] = { (const float*)d_in[11], (const float*)d_in[16], (const float*)d_in[21] };
    const float* eW2[3] = { (const float*)d_in[12], (const float*)d_in[17], (const float*)d_in[22] };
    const float* eb2[3] = { (const float*)d_in[13], (const float*)d_in[18], (const float*)d_in[23] };
    const float* bn1[3] = { (const float*)d_in[14], (const float*)d_in[19], (const float*)d_in[24] };
    const float* s21Wl = (const float*)d_in[25];
    const float* s21bl = (const float*)d_in[26];
    const float* s21Wr = (const float*)d_in[27];
    const float* bn21  = (const float*)d_in[28];
    const float* s3Wl[3] = { (const float*)d_in[29], (const float*)d_in[32], (const float*)d_in[35] };
    const float* s3bl[3] = { (const float*)d_in[30], (const float*)d_in[33], (const float*)d_in[36] };
    const float* s3Wr[3] = { (const float*)d_in[31], (const float*)d_in[34], (const float*)d_in[37] };

    char* ws = (char*)d_ws;
    unsigned short* Whl = (unsigned short*)(ws + OFF_WHL);
    float* WspP   = (float*)(ws + OFF_WSPP);
    float* bias01 = (float*)(ws + OFF_BIAS01);
    float* W1pqT  = (float*)(ws + OFF_W1PQT);
    float* biasPQ = (float*)(ws + OFF_BIASPQ);
    float* WsageT = (float*)(ws + OFF_WSAGET);
    float* bias21 = (float*)(ws + OFF_BIAS21);
    float* bnf    = (float*)(ws + OFF_BNF);
    f16*   W2h    = (f16*)(ws + OFF_W2BF);
    float* invc4  = (float*)(ws + OFF_INVC4);
    float* pz4    = (float*)(ws + OFF_PZ4);
    int*   rp     = (int*)(ws + OFF_RP);
    int*   parts  = (int*)(ws + OFF_PARTS);
    int*   deg    = (int*)(ws + OFF_DEG);
    unsigned int* cnt01 = (unsigned int*)(ws + OFF_CNT01);
    int*   ghead  = (int*)(ws + OFF_GHEAD);
    int*   sorted = (int*)(ws + OFF_SORT);
    unsigned int* ebuck = (unsigned int*)(ws + OFF_EBUCK);
    float* h      = (float*)(ws + OFF_H);
    f16*   Pi     = (f16*)(ws + OFF_PI);
    f16*   Qi     = (f16*)(ws + OFF_QI);
    f16*   y1i    = (f16*)(ws + OFF_Y1I);
    f16*   aggi   = (f16*)(ws + OFF_AGGI);   // overlays Pi (dead after edgeconv)

    hipMemsetAsync(ws + OFF_DEG, 0, 400128, stream);   // deg + cnt01

    k_prep<<<689, 256, 0, stream>>>(
        Wspf, bspf, W011, b011, W012, b012, bn01,
        eW1[0], eb1[0], eb2[0], bn1[0],
        eW1[1], eb1[1], eb2[1], bn1[1],
        eW1[2], eb1[2], eb2[2], bn1[2],
        eW2[0], eW2[1], eW2[2],
        s21Wl, s21bl, s21Wr, bn21,
        Whl, WspP, bias01, W1pqT, biasPQ, WsageT, bias21, bnf, W2h);

    k_hist<<<3907, 256, 0, stream>>>(ei + EE, attr, deg, cnt01);
    k_psum<<<NBK, 256, 0, stream>>>(deg, parts);
    k_pscan<<<1, 256, 0, stream>>>(parts, ghead);
    k_scanfix<<<NBK, 256, 0, stream>>>(deg, parts, rp);
    k_bucketA<<<245, 256, 0, stream>>>(ei, ei + EE, attr, ghead, ebuck);
    k_bucketB<<<NBK, 256, 0, stream>>>(rp, ebuck, sorted);

    k_h<<<3125, 256, 0, stream>>>(x, Whl, WspP, bias01, h);

    k_pq<<<782, 256, 0, stream>>>(h, W1pqT, biasPQ, Pi, Qi);

    k_edgeconv_f<<<PW_EC / 4, 256, 0, stream>>>(rp, cnt01, sorted, Pi, Qi, W2h, bnf, y1i, invc4);
    k_agg_f<<<PW_AG / 4, 256, 0, stream>>>(rp, cnt01, sorted, y1i, invc4, aggi);

    k_sage1<<<391, 256, 0, stream>>>(aggi, y1i, WsageT, bias21,
                                     s3Wl[0], s3bl[0], s3Wr[0],
                                     s3Wl[1], s3bl[1], s3Wr[1],
                                     s3Wl[2], s3bl[2], s3Wr[2], pz4);

    k_sage2_f<<<PW_AG / 4, 256, 0, stream>>>(rp, sorted, pz4, invc4, (float*)d_out);
}

// Round 10
// 749.356 us; speedup vs baseline: 1.0389x; 1.0389x over previous
//
#include <hip/hip_runtime.h>
#include <cstdint>
#include <cstddef>

#define NN 50000
#define EE 1000000
#define NBK 196          // dst buckets (dst>>8), 196*256 = 50176 >= NN
#define PW_EC 6144       // persistent waves, edgeconv (1536 blocks * 4; 6 blocks/CU LDS cap)
#define PW_AG 8192       // persistent waves, agg/sage2 (2048 blocks * 4)

typedef __attribute__((ext_vector_type(8))) short bf16x8;
typedef __attribute__((ext_vector_type(4))) short s16x4;
typedef __attribute__((ext_vector_type(4))) float f32x4;
typedef _Float16 f16;
typedef __attribute__((ext_vector_type(2))) _Float16 f16x2;
typedef __attribute__((ext_vector_type(4))) _Float16 f16x4;
typedef __attribute__((ext_vector_type(8))) _Float16 f16x8;

// truncation split: v == bf16(hi) + ~bf16(lo), residual ~2^-16 rel
__device__ __forceinline__ void split2(float v, short& hi, short& lo) {
    union { float f; unsigned int u; } a; a.f = v;
    unsigned short h16 = (unsigned short)(a.u >> 16);
    union { unsigned int u; float f; } hf; hf.u = ((unsigned int)h16) << 16;
    union { float f; unsigned int u; } b; b.f = v - hf.f;
    hi = (short)h16;
    lo = (short)(b.u >> 16);
}

// relu(p+q) in packed f16 (v_pk_add_f16 + v_pk_max_f16)
__device__ __forceinline__ f16x8 relupq(f16x8 p, f16x8 q) {
    f16x8 s = p + q;
    f16x8 z = {};
#if __has_builtin(__builtin_elementwise_max)
    return __builtin_elementwise_max(s, z);
#else
    f16x8 r;
#pragma unroll
    for (int j = 0; j < 8; j++) r[j] = (s[j] > (f16)0.f) ? s[j] : (f16)0.f;
    return r;
#endif
}

// ---------- workspace layout (byte offsets) ----------
#define OFF_WHL    ((size_t)0)          // 2*1024*64 bf16 = 262144
#define OFF_WSPP   ((size_t)262144)     // 64*4 f32
#define OFF_BIAS01 ((size_t)263168)     // 64 f32
#define OFF_W1PQT  ((size_t)263424)     // 3*64*128 f32
#define OFF_BIASPQ ((size_t)361728)     // 3*128 f32
#define OFF_WSAGET ((size_t)363264)     // 128*64 f32
#define OFF_BIAS21 ((size_t)396032)     // 64 f32
#define OFF_BNF    ((size_t)396288)     // 3*192 f32 (+pad to 2560)
#define OFF_W2BF   ((size_t)398848)     // 3*64*64 f16 = 24576
#define OFF_INVC4  ((size_t)423424)     // N*4 f32 = 800000 {ic1,ic2,ic3,0}
#define OFF_PZ4    ((size_t)1223424)    // N*4 f32 = 800000 {p1,p2,p3,zsum}
#define OFF_RP     ((size_t)2023424)    // (NN+1) i32 (+pad 200064)
#define OFF_PARTS  ((size_t)2223488)    // 256 i32 (+pad 4096)
#define OFF_DEG    ((size_t)2227584)    // N i32 (+pad 200064)
#define OFF_CNT01  ((size_t)2427648)    // N u32 (+pad 200064)  {c0 | c1<<16}, written by bucketB
#define OFF_GHEAD  ((size_t)2627712)    // NBK i32 (+pad 4096)
#define OFF_SORT   ((size_t)2631808)    // E i32 = 4000000 (src | attr<<16), attr-sorted within node
#define OFF_H      ((size_t)6631808)    // N*64 f32 = 12800000
#define OFF_PI     ((size_t)19431808)   // N*192 f16 = 19200000 (P, interleaved 3 branches)
#define OFF_QI     ((size_t)38631808)   // N*192 f16 = 19200000 (Q, interleaved)
#define OFF_Y1I    ((size_t)57831808)   // N*192 f16 = 19200000 (end 77031808)
#define OFF_EBUCK  OFF_H                // overlay: E u32, dead before k_h
#define OFF_AGGI   OFF_PI               // overlay: N*192 f16, Pi dead after edgeconv

// ---------- K1: weight prep / folding ----------
__global__ __launch_bounds__(256) void k_prep(
    const float* __restrict__ Wspf, const float* __restrict__ bspf,
    const float* __restrict__ W011, const float* __restrict__ b011,
    const float* __restrict__ W012, const float* __restrict__ b012,
    const float* __restrict__ bn01,
    const float* __restrict__ e1W1, const float* __restrict__ e1b1,
    const float* __restrict__ e1b2, const float* __restrict__ bn11,
    const float* __restrict__ e2W1, const float* __restrict__ e2b1,
    const float* __restrict__ e2b2, const float* __restrict__ bn12,
    const float* __restrict__ e3W1, const float* __restrict__ e3b1,
    const float* __restrict__ e3b2, const float* __restrict__ bn13,
    const float* __restrict__ e1W2, const float* __restrict__ e2W2,
    const float* __restrict__ e3W2,
    const float* __restrict__ s21Wl, const float* __restrict__ s21bl,
    const float* __restrict__ s21Wr, const float* __restrict__ bn21,
    unsigned short* __restrict__ Whl, float* __restrict__ WspP, float* __restrict__ bias01,
    float* __restrict__ W1pqT, float* __restrict__ biasPQ,
    float* __restrict__ WsageT, float* __restrict__ bias21, float* __restrict__ bnf,
    f16* __restrict__ W2h)
{
    int idx = blockIdx.x * 256 + threadIdx.x;
    if (idx < 131072) {
        int hl = idx >> 16;
        int r = idx & 65535;
        int kchunk = r >> 11;
        int r2 = r & 2047;
        int blk = r2 >> 9;
        int r3 = r2 & 511;
        int lane = r3 >> 3;
        int j = r3 & 7;
        int n = lane & 15, quad = lane >> 4;
        int k = kchunk * 32 + quad * 8 + j;
        int c = blk * 16 + n;
        float s = bn01[c] * rsqrtf(bn01[192 + c] + 1e-5f);
        float w = ((k < 512) ? W012[c * 512 + k] : W011[c * 576 + (k - 512)]) * s;
        short hi, lo;
        split2(w, hi, lo);
        Whl[idx] = (unsigned short)(hl ? lo : hi);
    } else if (idx < 131072 + 24576) {
        int r = idx - 131072;
        int b = r >> 13; r &= 8191;
        int k = r >> 7, cp = r & 127;
        const float* W1 = (b == 0) ? e1W1 : (b == 1) ? e2W1 : e3W1;
        float val;
        if (cp < 64) val = W1[cp * 128 + k] - W1[cp * 128 + 64 + k];
        else         val = W1[(cp - 64) * 128 + 64 + k];
        W1pqT[b * 8192 + k * 128 + cp] = val;
    } else if (idx < 131072 + 24576 + 8192) {
        int r = idx - (131072 + 24576);
        int k = r >> 6, c = r & 63;
        float s = bn21[c] * rsqrtf(bn21[192 + c] + 1e-5f);
        float w = (k < 64) ? s21Wl[c * 64 + k] : s21Wr[c * 64 + (k - 64)];
        WsageT[k * 64 + c] = w * s;
    } else if (idx < 131072 + 24576 + 8192 + 64) {
        int c = idx - (131072 + 24576 + 8192);
        float s01 = bn01[c] * rsqrtf(bn01[192 + c] + 1e-5f);
        float wsp0 = 0.f, wsp1 = 0.f, wsp2 = 0.f, wsp3 = 0.f, bacc = 0.f;
        for (int j = 0; j < 64; j++) {
            float w = W011[c * 576 + 512 + j];
            wsp0 += w * Wspf[j * 4 + 0];
            wsp1 += w * Wspf[j * 4 + 1];
            wsp2 += w * Wspf[j * 4 + 2];
            wsp3 += w * Wspf[j * 4 + 3];
            bacc += w * bspf[j];
        }
        WspP[c * 4 + 0] = wsp0 * s01; WspP[c * 4 + 1] = wsp1 * s01;
        WspP[c * 4 + 2] = wsp2 * s01; WspP[c * 4 + 3] = wsp3 * s01;
        bias01[c] = (b011[c] + b012[c] + bacc) * s01 + (bn01[64 + c] - bn01[128 + c] * s01);
        float s21 = bn21[c] * rsqrtf(bn21[192 + c] + 1e-5f);
        bias21[c] = s21bl[c] * s21 + (bn21[64 + c] - bn21[128 + c] * s21);
        const float* b1a[3] = { e1b1, e2b1, e3b1 };
        const float* b2a[3] = { e1b2, e2b2, e3b2 };
        const float* bna[3] = { bn11, bn12, bn13 };
#pragma unroll
        for (int b = 0; b < 3; b++) {
            float s = bna[b][c] * rsqrtf(bna[b][192 + c] + 1e-5f);
            float tr = bna[b][64 + c] - bna[b][128 + c] * s;
            bnf[b * 192 + c] = s;
            bnf[b * 192 + 64 + c] = b2a[b][c] * s + tr;
            bnf[b * 192 + 128 + c] = tr;
            biasPQ[b * 128 + c] = b1a[b][c];
            biasPQ[b * 128 + 64 + c] = 0.f;
        }
    } else if (idx < 131072 + 24576 + 8192 + 64 + 12288) {
        int r = idx - (131072 + 24576 + 8192 + 64);
        int b = r >> 12, i = r & 4095;
        const float* W2 = (b == 0) ? e1W2 : (b == 1) ? e2W2 : e3W2;
        W2h[b * 4096 + i] = (f16)W2[i];
    }
}

// ---------- degree histogram (deg only; class counts come from bucketB) ----------
__global__ __launch_bounds__(256) void k_hist(
    const int* __restrict__ dst, int* __restrict__ deg)
{
    int e = blockIdx.x * 256 + threadIdx.x;
    if (e < EE) atomicAdd(&deg[dst[e]], 1);
}

__global__ __launch_bounds__(256) void k_psum(const int* __restrict__ deg, int* __restrict__ parts)
{
    int i = blockIdx.x * 256 + threadIdx.x;
    int v = (i < NN) ? deg[i] : 0;
#pragma unroll
    for (int off = 32; off > 0; off >>= 1) v += __shfl_xor(v, off);
    __shared__ int ws4[4];
    int wid = threadIdx.x >> 6;
    if ((threadIdx.x & 63) == 0) ws4[wid] = v;
    __syncthreads();
    if (threadIdx.x == 0)
        parts[blockIdx.x] = ws4[0] + ws4[1] + ws4[2] + ws4[3];
}

// exclusive scan of bucket counts; also emits ghead (= bucket base = rp[b*256])
__global__ __launch_bounds__(256) void k_pscan(int* __restrict__ parts, int* __restrict__ ghead)
{
    __shared__ int sbuf[256];
    int tid = threadIdx.x;
    int v = (tid < NBK) ? parts[tid] : 0;
    sbuf[tid] = v;
    __syncthreads();
    for (int off = 1; off < 256; off <<= 1) {
        int t = (tid >= off) ? sbuf[tid - off] : 0;
        __syncthreads();
        sbuf[tid] += t;
        __syncthreads();
    }
    if (tid < NBK) {
        int ex = sbuf[tid] - v;
        parts[tid] = ex;
        ghead[tid] = ex;
    }
}

__global__ __launch_bounds__(256) void k_scanfix(
    const int* __restrict__ deg, const int* __restrict__ parts, int* __restrict__ rowptr)
{
    __shared__ int sbuf[256];
    int tid = threadIdx.x;
    int i = blockIdx.x * 256 + tid;
    int v = (i < NN) ? deg[i] : 0;
    sbuf[tid] = v;
    __syncthreads();
    for (int off = 1; off < 256; off <<= 1) {
        int t = (tid >= off) ? sbuf[tid - off] : 0;
        __syncthreads();
        sbuf[tid] += t;
        __syncthreads();
    }
    int base = parts[blockIdx.x];
    if (i < NN)      rowptr[i] = base + sbuf[tid] - v;
    if (i == NN - 1) rowptr[NN] = base + sbuf[tid];
}

// ---------- bucketed sort pass A: partition edges into dst-buckets ----------
__global__ __launch_bounds__(256) void k_bucketA(
    const int* __restrict__ src, const int* __restrict__ dst, const int* __restrict__ attr,
    int* __restrict__ ghead, unsigned int* __restrict__ ebuck)
{
    __shared__ int hist[NBK];
    __shared__ int head[NBK];
    int tid = threadIdx.x;
    if (tid < NBK) hist[tid] = 0;
    __syncthreads();
    int base_e = blockIdx.x * 4096;
    unsigned int word[16]; int bkt[16];
#pragma unroll
    for (int k = 0; k < 16; k++) {
        int e = base_e + k * 256 + tid;
        if (e < EE) {
            int d = dst[e], s = src[e], a = attr[e] + 1;
            int b = d >> 8;
            word[k] = (unsigned)s | ((unsigned)a << 16) | ((unsigned)(d & 255) << 18);
            bkt[k] = b;
            atomicAdd(&hist[b], 1);
        } else { bkt[k] = -1; word[k] = 0; }
    }
    __syncthreads();
    if (tid < NBK) {
        int c = hist[tid];
        head[tid] = c ? atomicAdd(&ghead[tid], c) : 0;
    }
    __syncthreads();
#pragma unroll
    for (int k = 0; k < 16; k++) {
        if (bkt[k] >= 0) {
            int pos = atomicAdd(&head[bkt[k]], 1);
            ebuck[pos] = word[k];
        }
    }
}

// ---------- bucketed sort pass B: sort by (dst&255, attr); emits cnt01 for free ----------
__global__ __launch_bounds__(256) void k_bucketB(
    const int* __restrict__ rp, const unsigned int* __restrict__ ebuck,
    int* __restrict__ sorted, unsigned int* __restrict__ cnt01)
{
    __shared__ int sbuf[1024];
    __shared__ int head[1024];
    __shared__ int s2[256];
    int b = blockIdx.x, tid = threadIdx.x;
    int n0 = b * 256;
    int n1 = n0 + 256; if (n1 > NN) n1 = NN;
    int r0 = rp[n0];
    int r1 = rp[n1];
    for (int i = tid; i < 1024; i += 256) sbuf[i] = 0;
    __syncthreads();
    for (int e = r0 + tid; e < r1; e += 256)
        atomicAdd(&sbuf[(ebuck[e] >> 16) & 1023], 1);    // key = (d&255)*4 + a
    __syncthreads();
    int i0 = tid * 4;                                    // thread tid owns node n0+tid
    int v0 = sbuf[i0], v1 = sbuf[i0 + 1], v2 = sbuf[i0 + 2], v3 = sbuf[i0 + 3];
    if (n0 + tid < NN)
        cnt01[n0 + tid] = (unsigned)v0 | ((unsigned)v1 << 16);
    int tot = v0 + v1 + v2 + v3;
    s2[tid] = tot;
    __syncthreads();
    for (int off = 1; off < 256; off <<= 1) {
        int t = (tid >= off) ? s2[tid - off] : 0;
        __syncthreads();
        s2[tid] += t;
        __syncthreads();
    }
    int ex = s2[tid] - tot;
    head[i0]     = r0 + ex;
    head[i0 + 1] = r0 + ex + v0;
    head[i0 + 2] = r0 + ex + v0 + v1;
    head[i0 + 3] = r0 + ex + v0 + v1 + v2;
    __syncthreads();
    for (int e = r0 + tid; e < r1; e += 256) {
        unsigned int w = ebuck[e];
        int pos = atomicAdd(&head[(w >> 16) & 1023], 1);
        sorted[pos] = (int)(w & 0x3FFFFu);   // src | attr<<16
    }
}

// ---------- K2: h = relu(fold_bn01(x @ Wc')) ----------
__global__ __launch_bounds__(256) void k_h(
    const float* __restrict__ x, const unsigned short* __restrict__ Whl,
    const float* __restrict__ WspP, const float* __restrict__ bias01,
    float* __restrict__ h)
{
    __shared__ unsigned short hib[2][4096];
    __shared__ unsigned short lob[2][4096];
    int tid = threadIdx.x;
    int w = tid >> 6, l = tid & 63;
    int tile = blockIdx.x;
    int m = l & 15, quad = l >> 4;
    int blk = w;
    const unsigned short* Wh = Whl;
    const unsigned short* Wl = Whl + 65536;
    const size_t xbase = (size_t)tile * 16 * 1028;

    int oct_w = l >> 1, off_w = (l & 1) * 4;

    f32x4 g[4];
#pragma unroll
    for (int p = 0; p < 4; p++)
        g[p] = *(const f32x4*)(x + xbase + (size_t)(p * 4 + w) * 1028 + l * 4);
#pragma unroll
    for (int p = 0; p < 4; p++) {
        int r = p * 4 + w;
        int op = r * 256 + (oct_w ^ (r & 7)) * 8 + off_w;
        s16x4 h4, l4;
#pragma unroll
        for (int i = 0; i < 4; i++) { short hi, lo; split2(g[p][i], hi, lo); h4[i] = hi; l4[i] = lo; }
        *(s16x4*)(&hib[0][op]) = h4;
        *(s16x4*)(&lob[0][op]) = l4;
    }
    __syncthreads();

    f32x4 acc = { 0.f, 0.f, 0.f, 0.f };
    for (int c = 0; c < 4; c++) {
        if (c < 3) {
#pragma unroll
            for (int p = 0; p < 4; p++)
                g[p] = *(const f32x4*)(x + xbase + (size_t)(p * 4 + w) * 1028 + (c + 1) * 256 + l * 4);
        }
        int buf = c & 1;
        const unsigned short* hp = &hib[buf][m * 256];
        const unsigned short* lp = &lob[buf][m * 256];
        int msw = m & 7;
#pragma unroll
        for (int ks = 0; ks < 8; ks++) {
            int oct = ks * 4 + quad;
            int ao = (oct ^ msw) * 8;
            bf16x8 xh = *(const bf16x8*)(hp + ao);
            bf16x8 xl = *(const bf16x8*)(lp + ao);
            int fb = (c * 8 + ks) * 2048 + blk * 512 + l * 8;
            bf16x8 bh = *(const bf16x8*)(Wh + fb);
            bf16x8 bl = *(const bf16x8*)(Wl + fb);
            acc = __builtin_amdgcn_mfma_f32_16x16x32_bf16(xh, bh, acc, 0, 0, 0);
            acc = __builtin_amdgcn_mfma_f32_16x16x32_bf16(xl, bh, acc, 0, 0, 0);
            acc = __builtin_amdgcn_mfma_f32_16x16x32_bf16(xh, bl, acc, 0, 0, 0);
        }
        if (c < 3) {
            int nbuf = (c + 1) & 1;
#pragma unroll
            for (int p = 0; p < 4; p++) {
                int r = p * 4 + w;
                int op = r * 256 + (oct_w ^ (r & 7)) * 8 + off_w;
                s16x4 h4, l4;
#pragma unroll
                for (int i = 0; i < 4; i++) { short hi, lo; split2(g[p][i], hi, lo); h4[i] = hi; l4[i] = lo; }
                *(s16x4*)(&hib[nbuf][op]) = h4;
                *(s16x4*)(&lob[nbuf][op]) = l4;
            }
            __syncthreads();
        }
    }

    int ch = blk * 16 + m;
    f32x4 wsp = *(const f32x4*)(WspP + ch * 4);
    float bia = bias01[ch];
#pragma unroll
    for (int r = 0; r < 4; r++) {
        int row = tile * 16 + quad * 4 + r;
        f32x4 sp = *(const f32x4*)(x + (size_t)row * 1028 + 1024);
        float a = acc[r] + sp[0] * wsp[0] + sp[1] * wsp[1]
                + sp[2] * wsp[2] + sp[3] * wsp[3] + bia;
        h[(size_t)row * 64 + ch] = fmaxf(a, 0.f);
    }
}

// ---------- K4: all 3 branches fused: P = h @ W1p' + b1 (f16), Q = h @ W1q' (f16) ----------
__global__ __launch_bounds__(256) void k_pq(
    const float* __restrict__ h, const float* __restrict__ WT3,
    const float* __restrict__ biasPQ, f16* __restrict__ Pi, f16* __restrict__ Qi)
{
    __shared__ float wt[64 * 128];
    __shared__ float xt[64 * 68];
    int tid = threadIdx.x;
    int m0 = blockIdx.x * 64;
    int cg = tid & 31, rg = tid >> 5;
#pragma unroll
    for (int i = 0; i < 4; i++) {
        int li = i * 256 + tid;
        int rr = li >> 4, q = li & 15;
        int row = m0 + rr;
        float4 u = make_float4(0.f, 0.f, 0.f, 0.f);
        if (row < NN) u = *(const float4*)(h + (size_t)row * 64 + q * 4);
        *(float4*)(xt + rr * 68 + q * 4) = u;
    }
    for (int b = 0; b < 3; b++) {
        __syncthreads();
#pragma unroll
        for (int i = 0; i < 8; i++)
            ((float4*)wt)[i * 256 + tid] = ((const float4*)(WT3 + b * 8192))[i * 256 + tid];
        __syncthreads();
        float acc[8][4];
#pragma unroll
        for (int r = 0; r < 8; r++)
#pragma unroll
            for (int j = 0; j < 4; j++) acc[r][j] = 0.f;
#pragma unroll 8
        for (int k = 0; k < 64; k++) {
            float4 wv = *(const float4*)(wt + k * 128 + cg * 4);
#pragma unroll
            for (int r = 0; r < 8; r++) {
                float xv = xt[(rg * 8 + r) * 68 + k];
                acc[r][0] += xv * wv.x; acc[r][1] += xv * wv.y;
                acc[r][2] += xv * wv.z; acc[r][3] += xv * wv.w;
            }
        }
        const float* biasP = biasPQ + b * 128;
#pragma unroll
        for (int r = 0; r < 8; r++) {
            int row = m0 + rg * 8 + r;
            if (row < NN) {
                if (cg < 16) {               // P half (+bias), fp16
                    f16x4 res;
#pragma unroll
                    for (int j = 0; j < 4; j++)
                        res[j] = (f16)(acc[r][j] + biasP[cg * 4 + j]);
                    *(f16x4*)(Pi + (size_t)row * 192 + b * 64 + cg * 4) = res;
                } else {                     // Q half, fp16
                    f16x4 res;
#pragma unroll
                    for (int j = 0; j < 4; j++)
                        res[j] = (f16)acc[r][j];
                    *(f16x4*)(Qi + (size_t)row * 192 + b * 64 + (cg - 16) * 4) = res;
                }
            }
        }
    }
}

// per-branch contiguous range: batches of 16, mask-free except tail row test.
#define ECV_BRANCH(B, EST, ECN)                                                    \
    {                                                                              \
        f16x8 pl = *(const f16x8*)(pr + (B) * 64 + quad * 8);                      \
        f16x8 ph = *(const f16x8*)(pr + (B) * 64 + 32 + quad * 8);                 \
        float acc[4][4];                                                           \
        _Pragma("unroll") for (int blk = 0; blk < 4; blk++)                        \
            _Pragma("unroll") for (int r = 0; r < 4; r++) acc[blk][r] = -3.0e38f;  \
        int nbF = (ECN) >> 4;                                                      \
        int rem = (ECN) & 15;                                                      \
        for (int bi = 0; bi < nbF; bi++) {                                         \
            int srcm = sorted[(EST) + bi * 16 + m] & 0xFFFF;                       \
            const f16* qr = Qi + (size_t)srcm * 192 + (B) * 64;                    \
            f16x8 q0 = *(const f16x8*)(qr + quad * 8);                             \
            f16x8 q1 = *(const f16x8*)(qr + 32 + quad * 8);                        \
            f16x8 a0 = relupq(pl, q0);                                             \
            f16x8 a1 = relupq(ph, q1);                                             \
            _Pragma("unroll") for (int blk = 0; blk < 4; blk++) {                  \
                f32x4 c = { 0.f, 0.f, 0.f, 0.f };                                  \
                f16x8 w0 = *(const f16x8*)(w2s + ((B) * 8 + blk * 2 + 0) * 512 + quad * 128 + m * 8); \
                f16x8 w1 = *(const f16x8*)(w2s + ((B) * 8 + blk * 2 + 1) * 512 + quad * 128 + m * 8); \
                c = __builtin_amdgcn_mfma_f32_16x16x32_f16(a0, w0, c, 0, 0, 0);    \
                c = __builtin_amdgcn_mfma_f32_16x16x32_f16(a1, w1, c, 0, 0, 0);    \
                _Pragma("unroll") for (int r = 0; r < 4; r++)                      \
                    acc[blk][r] = fmaxf(acc[blk][r], c[r]);                        \
            }                                                                      \
        }                                                                          \
        if (rem) {                                                                 \
            int e = (EST) + nbF * 16 + m;                                          \
            int srcm = sorted[(m < rem) ? e : (EST)] & 0xFFFF;                     \
            const f16* qr = Qi + (size_t)srcm * 192 + (B) * 64;                    \
            f16x8 q0 = *(const f16x8*)(qr + quad * 8);                             \
            f16x8 q1 = *(const f16x8*)(qr + 32 + quad * 8);                        \
            f16x8 a0 = relupq(pl, q0);                                             \
            f16x8 a1 = relupq(ph, q1);                                             \
            _Pragma("unroll") for (int blk = 0; blk < 4; blk++) {                  \
                f32x4 c = { 0.f, 0.f, 0.f, 0.f };                                  \
                f16x8 w0 = *(const f16x8*)(w2s + ((B) * 8 + blk * 2 + 0) * 512 + quad * 128 + m * 8); \
                f16x8 w1 = *(const f16x8*)(w2s + ((B) * 8 + blk * 2 + 1) * 512 + quad * 128 + m * 8); \
                c = __builtin_amdgcn_mfma_f32_16x16x32_f16(a0, w0, c, 0, 0, 0);    \
                c = __builtin_amdgcn_mfma_f32_16x16x32_f16(a1, w1, c, 0, 0, 0);    \
                _Pragma("unroll") for (int r = 0; r < 4; r++)                      \
                    if (quad * 4 + r < rem)                                        \
                        acc[blk][r] = fmaxf(acc[blk][r], c[r]);                    \
            }                                                                      \
        }                                                                          \
        float red[4];                                                              \
        _Pragma("unroll") for (int blk = 0; blk < 4; blk++) {                      \
            float rv = fmaxf(fmaxf(acc[blk][0], acc[blk][1]),                      \
                             fmaxf(acc[blk][2], acc[blk][3]));                     \
            rv = fmaxf(rv, __shfl_xor(rv, 16));                                    \
            rv = fmaxf(rv, __shfl_xor(rv, 32));                                    \
            red[blk] = rv;                                                         \
        }                                                                          \
        float mx = red[quad];                                                      \
        const float* scb = bnf + (B) * 192;                                        \
        float outv = ((ECN) > 0) ? fmaxf(fmaf(mx, scb[lane], scb[64 + lane]), 0.f) \
                                 : fmaxf(scb[128 + lane], 0.f);                    \
        y1i[(size_t)v * 192 + (B) * 64 + lane] = (f16)outv;                        \
    }

// ---------- K5: fused 3-branch EdgeConv; attr-sorted ranges; persistent waves ----------
__global__ __launch_bounds__(256) void k_edgeconv_f(
    const int* __restrict__ rowptr, const unsigned int* __restrict__ cnt01,
    const int* __restrict__ sorted,
    const f16* __restrict__ Pi, const f16* __restrict__ Qi,
    const f16* __restrict__ W2h,               // 3*64*64 f16
    const float* __restrict__ bnf,             // 3*192
    f16* __restrict__ y1i, float* __restrict__ invc4)
{
    __shared__ f16 w2s[12288];                 // 3 branches : 24 frags * 512 halves, bank-permuted
    int tid = threadIdx.x;
#pragma unroll
    for (int u0 = 0; u0 < 6; u0++) {
        int u = u0 * 256 + tid;                // 0..1535
        int frag = u >> 6;                     // b*8 + blk*2 + kc   (b in {0,1,2})
        int rem = u & 63;
        int m2 = rem >> 2, qd = rem & 3;
        int bb = frag >> 3, blk = (frag >> 1) & 3, kc = frag & 1;
        *(int4*)(w2s + frag * 512 + qd * 128 + m2 * 8) =
            *(const int4*)(W2h + (bb * 64 + blk * 16 + m2) * 64 + kc * 32 + qd * 8);
    }
    __syncthreads();

    int wid = tid >> 6, lane = tid & 63;
    int m = lane & 15, quad = lane >> 4;
    int gw = blockIdx.x * 4 + wid;             // persistent wave id, PW_EC total

    for (int v = gw; v < NN; v += PW_EC) {
        const f16* pr = Pi + (size_t)v * 192;
        int e0 = rowptr[v], e1 = rowptr[v + 1];
        int deg = e1 - e0;
        unsigned int cc = cnt01[v];
        int c0 = (int)(cc & 0xFFFFu);
        int c1 = (int)(cc >> 16);
        int n1cnt = deg - c0;                  // seg1 (a>=1): [e0+c0, e1)
        int n2cnt = c0 + c1;                   // seg2 (a<=1): [e0, e0+c0+c1)

        ECV_BRANCH(0, e0 + c0, n1cnt)
        ECV_BRANCH(1, e0, n2cnt)
        ECV_BRANCH(2, e0, deg)

        if (lane == 0) {
            float4 ic;
            ic.x = 1.f / (float)(n1cnt > 0 ? n1cnt : 1);
            ic.y = 1.f / (float)(n2cnt > 0 ? n2cnt : 1);
            ic.z = 1.f / (float)(deg   > 0 ? deg   : 1);
            ic.w = 0.f;
            *(float4*)(invc4 + (size_t)v * 4) = ic;
        }
    }
}

// per-branch range mean: 8 lanes/edge, unconditional f16x8 loads
#define AGG_BRANCH(B, EST, ECN, ICS)                                               \
    {                                                                              \
        float s[8];                                                                \
        _Pragma("unroll") for (int j = 0; j < 8; j++) s[j] = 0.f;                  \
        for (int eb = 0; eb < (ECN); eb += 8) {                                    \
            if (eb + eslot < (ECN)) {                                              \
                int src = sorted[(EST) + eb + eslot] & 0xFFFF;                     \
                f16x8 u = *(const f16x8*)(y1i + (size_t)src * 192 + (B) * 64 + cg * 8); \
                _Pragma("unroll") for (int j = 0; j < 8; j++) s[j] += (float)u[j]; \
            }                                                                      \
        }                                                                          \
        _Pragma("unroll") for (int j = 0; j < 8; j++) {                            \
            s[j] += __shfl_xor(s[j], 8);                                           \
            s[j] += __shfl_xor(s[j], 16);                                          \
            s[j] += __shfl_xor(s[j], 32);                                          \
        }                                                                          \
        if (eslot == 0) {                                                          \
            f16x8 r;                                                               \
            _Pragma("unroll") for (int j = 0; j < 8; j++) r[j] = (f16)(s[j] * (ICS)); \
            *(f16x8*)(aggi + (size_t)v * 192 + (B) * 64 + cg * 8) = r;             \
        }                                                                          \
    }

// ---------- K6a: fused 3-branch mean aggregation; attr-sorted ranges ----------
__global__ __launch_bounds__(256) void k_agg_f(
    const int* __restrict__ rowptr, const unsigned int* __restrict__ cnt01,
    const int* __restrict__ sorted,
    const f16* __restrict__ y1i, const float* __restrict__ invc4,
    f16* __restrict__ aggi)
{
    int wid = threadIdx.x >> 6, lane = threadIdx.x & 63;
    int eslot = lane >> 3, cg = lane & 7;
    int gw = blockIdx.x * 4 + wid;
    for (int v = gw; v < NN; v += PW_AG) {
        int e0 = rowptr[v], e1 = rowptr[v + 1];
        int deg = e1 - e0;
        unsigned int cc = cnt01[v];
        int c0 = (int)(cc & 0xFFFFu);
        int c1 = (int)(cc >> 16);
        float4 icv = *(const float4*)(invc4 + (size_t)v * 4);
        AGG_BRANCH(0, e0 + c0, deg - c0, icv.x)
        AGG_BRANCH(1, e0, c0 + c1, icv.y)
        AGG_BRANCH(2, e0, deg, icv.z)
    }
}

// ---------- K6b: sage1 + fused proj, all 3 branches in one kernel ----------
__global__ __launch_bounds__(256) void k_sage1(
    const f16* __restrict__ aggi, const f16* __restrict__ y1i,
    const float* __restrict__ WsageT, const float* __restrict__ bias21,
    const float* __restrict__ Wl0, const float* __restrict__ bl0, const float* __restrict__ Wr0,
    const float* __restrict__ Wl1, const float* __restrict__ bl1, const float* __restrict__ Wr1,
    const float* __restrict__ Wl2, const float* __restrict__ bl2, const float* __restrict__ Wr2,
    float* __restrict__ pz4)
{
    __shared__ float wt[64 * 64];
    __shared__ float xt[128 * 68];
    __shared__ float wl[64], wr[64];
    int tid = threadIdx.x;
    int m0 = blockIdx.x * 128;
    int cg = tid & 15, rg = tid >> 4;
    float zsum[8];
#pragma unroll
    for (int r = 0; r < 8; r++) zsum[r] = 0.f;

    for (int b = 0; b < 3; b++) {
        const float* Wl3 = (b == 0) ? Wl0 : (b == 1) ? Wl1 : Wl2;
        const float* bl3 = (b == 0) ? bl0 : (b == 1) ? bl1 : bl2;
        const float* Wr3 = (b == 0) ? Wr0 : (b == 1) ? Wr1 : Wr2;
        __syncthreads();                     // guard wl/wr overwrite vs prior epilogue reads
        if (tid < 64) { wl[tid] = Wl3[tid]; wr[tid] = Wr3[tid]; }
        float blv = bl3[0];
        float acc[8][4];
#pragma unroll
        for (int r = 0; r < 8; r++)
#pragma unroll
            for (int j = 0; j < 4; j++) acc[r][j] = 0.f;
        for (int ch = 0; ch < 2; ch++) {
            const f16* A = (ch ? y1i : aggi) + b * 64;
            __syncthreads();
#pragma unroll
            for (int i = 0; i < 4; i++)
                ((float4*)wt)[i * 256 + tid] = ((const float4*)(WsageT + ch * 4096))[i * 256 + tid];
#pragma unroll
            for (int i = 0; i < 4; i++) {
                int li = i * 256 + tid;
                int rr = li >> 3, q = li & 7;
                int row = m0 + rr;
                f16x8 u = {};
                if (row < NN) u = *(const f16x8*)(A + (size_t)row * 192 + q * 8);
                float4 lo4 = make_float4((float)u[0], (float)u[1], (float)u[2], (float)u[3]);
                float4 hi4 = make_float4((float)u[4], (float)u[5], (float)u[6], (float)u[7]);
                *(float4*)(xt + rr * 68 + q * 8) = lo4;
                *(float4*)(xt + rr * 68 + q * 8 + 4) = hi4;
            }
            __syncthreads();
#pragma unroll 8
            for (int k = 0; k < 64; k++) {
                float4 wv = *(const float4*)(wt + k * 64 + cg * 4);
#pragma unroll
                for (int r = 0; r < 8; r++) {
                    float xv = xt[(rg * 8 + r) * 68 + k];
                    acc[r][0] += xv * wv.x; acc[r][1] += xv * wv.y;
                    acc[r][2] += xv * wv.z; acc[r][3] += xv * wv.w;
                }
            }
        }
#pragma unroll
        for (int r = 0; r < 8; r++) {
            int row = m0 + rg * 8 + r;
            float ap = 0.f, az = 0.f;
#pragma unroll
            for (int j = 0; j < 4; j++) {
                float t = fmaxf(acc[r][j] + bias21[cg * 4 + j], 0.f);
                ap += t * wl[cg * 4 + j];
                az += t * wr[cg * 4 + j];
            }
            ap += __shfl_xor(ap, 1); ap += __shfl_xor(ap, 2);
            ap += __shfl_xor(ap, 4); ap += __shfl_xor(ap, 8);
            az += __shfl_xor(az, 1); az += __shfl_xor(az, 2);
            az += __shfl_xor(az, 4); az += __shfl_xor(az, 8);
            zsum[r] += az + blv;
            if (cg == 0 && row < NN)
                pz4[(size_t)row * 4 + b] = ap;
        }
    }
#pragma unroll
    for (int r = 0; r < 8; r++) {
        int row = m0 + rg * 8 + r;
        if (cg == 0 && row < NN)
            pz4[(size_t)row * 4 + 3] = zsum[r];
    }
}

// ---------- K8: fused 3-branch sage2 + sigmoid; 16 lanes/node, persistent ----------
__global__ __launch_bounds__(256) void k_sage2_f(
    const int* __restrict__ rowptr, const int* __restrict__ sorted,
    const float* __restrict__ pz4, const float* __restrict__ invc4,
    float* __restrict__ outp)
{
    int wid = threadIdx.x >> 6, lane = threadIdx.x & 63;
    int sub = lane >> 4, sl = lane & 15;       // 4 sub-groups of 16 lanes per wave
    int gw = blockIdx.x * 4 + wid;
    for (int v = gw * 4 + sub; v < NN; v += PW_AG * 4) {
        int e0 = rowptr[v], e1 = rowptr[v + 1];
        float s1 = 0.f, s2 = 0.f, s3 = 0.f;
        for (int e = e0 + sl; e < e1; e += 16) {
            int w = sorted[e];
            int src = w & 0xFFFF, a = (w >> 16) & 3;
            float4 pz = *(const float4*)(pz4 + (size_t)src * 4);
            s3 += pz.z;
            if (a >= 1) s1 += pz.x;
            if (a <= 1) s2 += pz.y;
        }
#pragma unroll
        for (int off = 1; off < 16; off <<= 1) {
            s1 += __shfl_xor(s1, off);
            s2 += __shfl_xor(s2, off);
            s3 += __shfl_xor(s3, off);
        }
        if (sl == 0) {
            float4 icv = *(const float4*)(invc4 + (size_t)v * 4);
            float zsum = pz4[(size_t)v * 4 + 3];
            float val = s1 * icv.x + s2 * icv.y + s3 * icv.z + zsum;
            outp[v] = 1.f / (1.f + expf(-val));
        }
    }
}

// ---------- launch ----------
extern "C" void kernel_launch(void* const* d_in, const int* in_sizes, int n_in,
                              void* d_out, int out_size, void* d_ws, size_t ws_size,
                              hipStream_t stream)
{
    const float* x    = (const float*)d_in[0];
    const int* ei     = (const int*)d_in[1];
    const int* attr   = (const int*)d_in[2];
    const float* Wspf = (const float*)d_in[3];
    const float* bspf = (const float*)d_in[4];
    const float* W011 = (const float*)d_in[5];
    const float* b011 = (const float*)d_in[6];
    const float* W012 = (const float*)d_in[7];
    const float* b012 = (const float*)d_in[8];
    const float* bn01 = (const float*)d_in[9];
    const float* eW1[3] = { (const float*)d_in[10], (const float*)d_in[15], (const float*)d_in[20] };
    const float* eb1[3] = { (const float*)d_in[11], (const float*)d_in[16], (const float*)d_in[21] };
    const float* eW2[3] = { (const float*)d_in[12], (const float*)d_in[17], (const float*)d_in[22] };
    const float* eb2[3] = { (const float*)d_in[13], (const float*)d_in[18], (const float*)d_in[23] };
    const float* bn1[3] = { (const float*)d_in[14], (const float*)d_in[19], (const float*)d_in[24] };
    const float* s21Wl = (const float*)d_in[25];
    const float* s21bl = (const float*)d_in[26];
    const float* s21Wr = (const float*)d_in[27];
    const float* bn21  = (const float*)d_in[28];
    const float* s3Wl[3] = { (const float*)d_in[29], (const float*)d_in[32], (const float*)d_in[35] };
    const float* s3bl[3] = { (const float*)d_in[30], (const float*)d_in[33], (const float*)d_in[36] };
    const float* s3Wr[3] = { (const float*)d_in[31], (const float*)d_in[34], (const float*)d_in[37] };

    char* ws = (char*)d_ws;
    unsigned short* Whl = (unsigned short*)(ws + OFF_WHL);
    float* WspP   = (float*)(ws + OFF_WSPP);
    float* bias01 = (float*)(ws + OFF_BIAS01);
    float* W1pqT  = (float*)(ws + OFF_W1PQT);
    float* biasPQ = (float*)(ws + OFF_BIASPQ);
    float* WsageT = (float*)(ws + OFF_WSAGET);
    float* bias21 = (float*)(ws + OFF_BIAS21);
    float* bnf    = (float*)(ws + OFF_BNF);
    f16*   W2h    = (f16*)(ws + OFF_W2BF);
    float* invc4  = (float*)(ws + OFF_INVC4);
    float* pz4    = (float*)(ws + OFF_PZ4);
    int*   rp     = (int*)(ws + OFF_RP);
    int*   parts  = (int*)(ws + OFF_PARTS);
    int*   deg    = (int*)(ws + OFF_DEG);
    unsigned int* cnt01 = (unsigned int*)(ws + OFF_CNT01);
    int*   ghead  = (int*)(ws + OFF_GHEAD);
    int*   sorted = (int*)(ws + OFF_SORT);
    unsigned int* ebuck = (unsigned int*)(ws + OFF_EBUCK);
    float* h      = (float*)(ws + OFF_H);
    f16*   Pi     = (f16*)(ws + OFF_PI);
    f16*   Qi     = (f16*)(ws + OFF_QI);
    f16*   y1i    = (f16*)(ws + OFF_Y1I);
    f16*   aggi   = (f16*)(ws + OFF_AGGI);   // overlays Pi (dead after edgeconv)

    hipMemsetAsync(ws + OFF_DEG, 0, 200064, stream);   // deg only (cnt01 fully written by bucketB)

    k_prep<<<689, 256, 0, stream>>>(
        Wspf, bspf, W011, b011, W012, b012, bn01,
        eW1[0], eb1[0], eb2[0], bn1[0],
        eW1[1], eb1[1], eb2[1], bn1[1],
        eW1[2], eb1[2], eb2[2], bn1[2],
        eW2[0], eW2[1], eW2[2],
        s21Wl, s21bl, s21Wr, bn21,
        Whl, WspP, bias01, W1pqT, biasPQ, WsageT, bias21, bnf, W2h);

    k_hist<<<3907, 256, 0, stream>>>(ei + EE, deg);
    k_psum<<<NBK, 256, 0, stream>>>(deg, parts);
    k_pscan<<<1, 256, 0, stream>>>(parts, ghead);
    k_scanfix<<<NBK, 256, 0, stream>>>(deg, parts, rp);
    k_bucketA<<<245, 256, 0, stream>>>(ei, ei + EE, attr, ghead, ebuck);
    k_bucketB<<<NBK, 256, 0, stream>>>(rp, ebuck, sorted, cnt01);

    k_h<<<3125, 256, 0, stream>>>(x, Whl, WspP, bias01, h);

    k_pq<<<782, 256, 0, stream>>>(h, W1pqT, biasPQ, Pi, Qi);

    k_edgeconv_f<<<PW_EC / 4, 256, 0, stream>>>(rp, cnt01, sorted, Pi, Qi, W2h, bnf, y1i, invc4);
    k_agg_f<<<PW_AG / 4, 256, 0, stream>>>(rp, cnt01, sorted, y1i, invc4, aggi);

    k_sage1<<<391, 256, 0, stream>>>(aggi, y1i, WsageT, bias21,
                                     s3Wl[0], s3bl[0], s3Wr[0],
                                     s3Wl[1], s3bl[1], s3Wr[1],
                                     s3Wl[2], s3bl[2], s3Wr[2], pz4);

    k_sage2_f<<<PW_AG / 4, 256, 0, stream>>>(rp, sorted, pz4, invc4, (float*)d_out);
}

// Round 11
// 711.379 us; speedup vs baseline: 1.0944x; 1.0534x over previous
//
#include <hip/hip_runtime.h>
#include <cstdint>
#include <cstddef>

#define NN 50000
#define EE 1000000
#define NBK 196          // dst buckets (dst>>8), 196*256 = 50176 >= NN
#define PW_EC 6144       // persistent waves, edgeconv (1536 blocks * 4; 6 blocks/CU LDS cap)
#define PW_AG 8192       // persistent waves, agg/sage2 (2048 blocks * 4)
#define SG_PAD 136       // Wsage LDS row pad (f16 units): 2-way bank aliasing = free

typedef __attribute__((ext_vector_type(8))) short bf16x8;
typedef __attribute__((ext_vector_type(4))) short s16x4;
typedef __attribute__((ext_vector_type(4))) float f32x4;
typedef _Float16 f16;
typedef __attribute__((ext_vector_type(2))) _Float16 f16x2;
typedef __attribute__((ext_vector_type(4))) _Float16 f16x4;
typedef __attribute__((ext_vector_type(8))) _Float16 f16x8;

// truncation split: v == bf16(hi) + ~bf16(lo), residual ~2^-16 rel
__device__ __forceinline__ void split2(float v, short& hi, short& lo) {
    union { float f; unsigned int u; } a; a.f = v;
    unsigned short h16 = (unsigned short)(a.u >> 16);
    union { unsigned int u; float f; } hf; hf.u = ((unsigned int)h16) << 16;
    union { float f; unsigned int u; } b; b.f = v - hf.f;
    hi = (short)h16;
    lo = (short)(b.u >> 16);
}

// relu(p+q) in packed f16 (v_pk_add_f16 + v_pk_max_f16)
__device__ __forceinline__ f16x8 relupq(f16x8 p, f16x8 q) {
    f16x8 s = p + q;
    f16x8 z = {};
#if __has_builtin(__builtin_elementwise_max)
    return __builtin_elementwise_max(s, z);
#else
    f16x8 r;
#pragma unroll
    for (int j = 0; j < 8; j++) r[j] = (s[j] > (f16)0.f) ? s[j] : (f16)0.f;
    return r;
#endif
}

// ---------- workspace layout (byte offsets) ----------
#define OFF_WHL    ((size_t)0)          // 2*1024*64 bf16 = 262144
#define OFF_WSPP   ((size_t)262144)     // 64*4 f32
#define OFF_BIAS01 ((size_t)263168)     // 64 f32
#define OFF_W1PQT  ((size_t)263424)     // 3*64*128 f32
#define OFF_BIASPQ ((size_t)361728)     // 3*128 f32
#define OFF_WSAGET ((size_t)363264)     // 64*128 f16 = 16384 (in 32KB slot)
#define OFF_BIAS21 ((size_t)396032)     // 64 f32
#define OFF_BNF    ((size_t)396288)     // 3*192 f32 (+pad to 2560)
#define OFF_W2BF   ((size_t)398848)     // 3*64*64 f16 = 24576
#define OFF_INVC4  ((size_t)423424)     // N*4 f32 = 800000 {ic1,ic2,ic3,0}
#define OFF_PZ4    ((size_t)1223424)    // N*4 f32 = 800000 {p1,p2,p3,zsum}
#define OFF_RP     ((size_t)2023424)    // (NN+1) i32 (+pad 200064)
#define OFF_PARTS  ((size_t)2223488)    // 256 i32 (+pad 4096)
#define OFF_DEG    ((size_t)2227584)    // N i32 (+pad 200064)
#define OFF_CNT01  ((size_t)2427648)    // N u32 (+pad 200064)  {c0 | c1<<16}, written by bucketB
#define OFF_GHEAD  ((size_t)2627712)    // NBK i32 (+pad 4096)
#define OFF_SORT   ((size_t)2631808)    // E i32 = 4000000 (src | attr<<16), attr-sorted within node
#define OFF_H      ((size_t)6631808)    // N*64 f32 = 12800000
#define OFF_PI     ((size_t)19431808)   // N*192 f16 = 19200000 (P, interleaved 3 branches)
#define OFF_QI     ((size_t)38631808)   // N*192 f16 = 19200000 (Q, interleaved)
#define OFF_Y1I    ((size_t)57831808)   // N*192 f16 = 19200000 (end 77031808)
#define OFF_EBUCK  OFF_H                // overlay: E u32, dead before k_h
#define OFF_AGGI   OFF_PI               // overlay: N*192 f16, Pi dead after edgeconv

// ---------- K1: weight prep / folding ----------
__global__ __launch_bounds__(256) void k_prep(
    const float* __restrict__ Wspf, const float* __restrict__ bspf,
    const float* __restrict__ W011, const float* __restrict__ b011,
    const float* __restrict__ W012, const float* __restrict__ b012,
    const float* __restrict__ bn01,
    const float* __restrict__ e1W1, const float* __restrict__ e1b1,
    const float* __restrict__ e1b2, const float* __restrict__ bn11,
    const float* __restrict__ e2W1, const float* __restrict__ e2b1,
    const float* __restrict__ e2b2, const float* __restrict__ bn12,
    const float* __restrict__ e3W1, const float* __restrict__ e3b1,
    const float* __restrict__ e3b2, const float* __restrict__ bn13,
    const float* __restrict__ e1W2, const float* __restrict__ e2W2,
    const float* __restrict__ e3W2,
    const float* __restrict__ s21Wl, const float* __restrict__ s21bl,
    const float* __restrict__ s21Wr, const float* __restrict__ bn21,
    unsigned short* __restrict__ Whl, float* __restrict__ WspP, float* __restrict__ bias01,
    float* __restrict__ W1pqT, float* __restrict__ biasPQ,
    f16* __restrict__ Wsg16, float* __restrict__ bias21, float* __restrict__ bnf,
    f16* __restrict__ W2h)
{
    int idx = blockIdx.x * 256 + threadIdx.x;
    if (idx < 131072) {
        int hl = idx >> 16;
        int r = idx & 65535;
        int kchunk = r >> 11;
        int r2 = r & 2047;
        int blk = r2 >> 9;
        int r3 = r2 & 511;
        int lane = r3 >> 3;
        int j = r3 & 7;
        int n = lane & 15, quad = lane >> 4;
        int k = kchunk * 32 + quad * 8 + j;
        int c = blk * 16 + n;
        float s = bn01[c] * rsqrtf(bn01[192 + c] + 1e-5f);
        float w = ((k < 512) ? W012[c * 512 + k] : W011[c * 576 + (k - 512)]) * s;
        short hi, lo;
        split2(w, hi, lo);
        Whl[idx] = (unsigned short)(hl ? lo : hi);
    } else if (idx < 131072 + 24576) {
        int r = idx - 131072;
        int b = r >> 13; r &= 8191;
        int k = r >> 7, cp = r & 127;
        const float* W1 = (b == 0) ? e1W1 : (b == 1) ? e2W1 : e3W1;
        float val;
        if (cp < 64) val = W1[cp * 128 + k] - W1[cp * 128 + 64 + k];
        else         val = W1[(cp - 64) * 128 + 64 + k];
        W1pqT[b * 8192 + k * 128 + cp] = val;
    } else if (idx < 131072 + 24576 + 8192) {
        int r = idx - (131072 + 24576);
        int k = r >> 6, c = r & 63;
        float s = bn21[c] * rsqrtf(bn21[192 + c] + 1e-5f);
        float w = (k < 64) ? s21Wl[c * 64 + k] : s21Wr[c * 64 + (k - 64)];
        Wsg16[c * 128 + k] = (f16)(w * s);
    } else if (idx < 131072 + 24576 + 8192 + 64) {
        int c = idx - (131072 + 24576 + 8192);
        float s01 = bn01[c] * rsqrtf(bn01[192 + c] + 1e-5f);
        float wsp0 = 0.f, wsp1 = 0.f, wsp2 = 0.f, wsp3 = 0.f, bacc = 0.f;
        for (int j = 0; j < 64; j++) {
            float w = W011[c * 576 + 512 + j];
            wsp0 += w * Wspf[j * 4 + 0];
            wsp1 += w * Wspf[j * 4 + 1];
            wsp2 += w * Wspf[j * 4 + 2];
            wsp3 += w * Wspf[j * 4 + 3];
            bacc += w * bspf[j];
        }
        WspP[c * 4 + 0] = wsp0 * s01; WspP[c * 4 + 1] = wsp1 * s01;
        WspP[c * 4 + 2] = wsp2 * s01; WspP[c * 4 + 3] = wsp3 * s01;
        bias01[c] = (b011[c] + b012[c] + bacc) * s01 + (bn01[64 + c] - bn01[128 + c] * s01);
        float s21 = bn21[c] * rsqrtf(bn21[192 + c] + 1e-5f);
        bias21[c] = s21bl[c] * s21 + (bn21[64 + c] - bn21[128 + c] * s21);
        const float* b1a[3] = { e1b1, e2b1, e3b1 };
        const float* b2a[3] = { e1b2, e2b2, e3b2 };
        const float* bna[3] = { bn11, bn12, bn13 };
#pragma unroll
        for (int b = 0; b < 3; b++) {
            float s = bna[b][c] * rsqrtf(bna[b][192 + c] + 1e-5f);
            float tr = bna[b][64 + c] - bna[b][128 + c] * s;
            bnf[b * 192 + c] = s;
            bnf[b * 192 + 64 + c] = b2a[b][c] * s + tr;
            bnf[b * 192 + 128 + c] = tr;
            biasPQ[b * 128 + c] = b1a[b][c];
            biasPQ[b * 128 + 64 + c] = 0.f;
        }
    } else if (idx < 131072 + 24576 + 8192 + 64 + 12288) {
        int r = idx - (131072 + 24576 + 8192 + 64);
        int b = r >> 12, i = r & 4095;
        const float* W2 = (b == 0) ? e1W2 : (b == 1) ? e2W2 : e3W2;
        W2h[b * 4096 + i] = (f16)W2[i];
    }
}

// ---------- degree histogram (deg only; class counts come from bucketB) ----------
__global__ __launch_bounds__(256) void k_hist(
    const int* __restrict__ dst, int* __restrict__ deg)
{
    int e = blockIdx.x * 256 + threadIdx.x;
    if (e < EE) atomicAdd(&deg[dst[e]], 1);
}

__global__ __launch_bounds__(256) void k_psum(const int* __restrict__ deg, int* __restrict__ parts)
{
    int i = blockIdx.x * 256 + threadIdx.x;
    int v = (i < NN) ? deg[i] : 0;
#pragma unroll
    for (int off = 32; off > 0; off >>= 1) v += __shfl_xor(v, off);
    __shared__ int ws4[4];
    int wid = threadIdx.x >> 6;
    if ((threadIdx.x & 63) == 0) ws4[wid] = v;
    __syncthreads();
    if (threadIdx.x == 0)
        parts[blockIdx.x] = ws4[0] + ws4[1] + ws4[2] + ws4[3];
}

// exclusive scan of bucket counts; also emits ghead (= bucket base = rp[b*256])
__global__ __launch_bounds__(256) void k_pscan(int* __restrict__ parts, int* __restrict__ ghead)
{
    __shared__ int sbuf[256];
    int tid = threadIdx.x;
    int v = (tid < NBK) ? parts[tid] : 0;
    sbuf[tid] = v;
    __syncthreads();
    for (int off = 1; off < 256; off <<= 1) {
        int t = (tid >= off) ? sbuf[tid - off] : 0;
        __syncthreads();
        sbuf[tid] += t;
        __syncthreads();
    }
    if (tid < NBK) {
        int ex = sbuf[tid] - v;
        parts[tid] = ex;
        ghead[tid] = ex;
    }
}

__global__ __launch_bounds__(256) void k_scanfix(
    const int* __restrict__ deg, const int* __restrict__ parts, int* __restrict__ rowptr)
{
    __shared__ int sbuf[256];
    int tid = threadIdx.x;
    int i = blockIdx.x * 256 + tid;
    int v = (i < NN) ? deg[i] : 0;
    sbuf[tid] = v;
    __syncthreads();
    for (int off = 1; off < 256; off <<= 1) {
        int t = (tid >= off) ? sbuf[tid - off] : 0;
        __syncthreads();
        sbuf[tid] += t;
        __syncthreads();
    }
    int base = parts[blockIdx.x];
    if (i < NN)      rowptr[i] = base + sbuf[tid] - v;
    if (i == NN - 1) rowptr[NN] = base + sbuf[tid];
}

// ---------- bucketed sort pass A: partition edges into dst-buckets ----------
__global__ __launch_bounds__(256) void k_bucketA(
    const int* __restrict__ src, const int* __restrict__ dst, const int* __restrict__ attr,
    int* __restrict__ ghead, unsigned int* __restrict__ ebuck)
{
    __shared__ int hist[NBK];
    __shared__ int head[NBK];
    int tid = threadIdx.x;
    if (tid < NBK) hist[tid] = 0;
    __syncthreads();
    int base_e = blockIdx.x * 4096;
    unsigned int word[16]; int bkt[16];
#pragma unroll
    for (int k = 0; k < 16; k++) {
        int e = base_e + k * 256 + tid;
        if (e < EE) {
            int d = dst[e], s = src[e], a = attr[e] + 1;
            int b = d >> 8;
            word[k] = (unsigned)s | ((unsigned)a << 16) | ((unsigned)(d & 255) << 18);
            bkt[k] = b;
            atomicAdd(&hist[b], 1);
        } else { bkt[k] = -1; word[k] = 0; }
    }
    __syncthreads();
    if (tid < NBK) {
        int c = hist[tid];
        head[tid] = c ? atomicAdd(&ghead[tid], c) : 0;
    }
    __syncthreads();
#pragma unroll
    for (int k = 0; k < 16; k++) {
        if (bkt[k] >= 0) {
            int pos = atomicAdd(&head[bkt[k]], 1);
            ebuck[pos] = word[k];
        }
    }
}

// ---------- bucketed sort pass B: sort by (dst&255, attr); emits cnt01 for free ----------
__global__ __launch_bounds__(256) void k_bucketB(
    const int* __restrict__ rp, const unsigned int* __restrict__ ebuck,
    int* __restrict__ sorted, unsigned int* __restrict__ cnt01)
{
    __shared__ int sbuf[1024];
    __shared__ int head[1024];
    __shared__ int s2[256];
    int b = blockIdx.x, tid = threadIdx.x;
    int n0 = b * 256;
    int n1 = n0 + 256; if (n1 > NN) n1 = NN;
    int r0 = rp[n0];
    int r1 = rp[n1];
    for (int i = tid; i < 1024; i += 256) sbuf[i] = 0;
    __syncthreads();
    for (int e = r0 + tid; e < r1; e += 256)
        atomicAdd(&sbuf[(ebuck[e] >> 16) & 1023], 1);    // key = (d&255)*4 + a
    __syncthreads();
    int i0 = tid * 4;                                    // thread tid owns node n0+tid
    int v0 = sbuf[i0], v1 = sbuf[i0 + 1], v2 = sbuf[i0 + 2], v3 = sbuf[i0 + 3];
    if (n0 + tid < NN)
        cnt01[n0 + tid] = (unsigned)v0 | ((unsigned)v1 << 16);
    int tot = v0 + v1 + v2 + v3;
    s2[tid] = tot;
    __syncthreads();
    for (int off = 1; off < 256; off <<= 1) {
        int t = (tid >= off) ? s2[tid - off] : 0;
        __syncthreads();
        s2[tid] += t;
        __syncthreads();
    }
    int ex = s2[tid] - tot;
    head[i0]     = r0 + ex;
    head[i0 + 1] = r0 + ex + v0;
    head[i0 + 2] = r0 + ex + v0 + v1;
    head[i0 + 3] = r0 + ex + v0 + v1 + v2;
    __syncthreads();
    for (int e = r0 + tid; e < r1; e += 256) {
        unsigned int w = ebuck[e];
        int pos = atomicAdd(&head[(w >> 16) & 1023], 1);
        sorted[pos] = (int)(w & 0x3FFFFu);   // src | attr<<16
    }
}

// ---------- K2: h = relu(fold_bn01(x @ Wc')) ----------
__global__ __launch_bounds__(256) void k_h(
    const float* __restrict__ x, const unsigned short* __restrict__ Whl,
    const float* __restrict__ WspP, const float* __restrict__ bias01,
    float* __restrict__ h)
{
    __shared__ unsigned short hib[2][4096];
    __shared__ unsigned short lob[2][4096];
    int tid = threadIdx.x;
    int w = tid >> 6, l = tid & 63;
    int tile = blockIdx.x;
    int m = l & 15, quad = l >> 4;
    int blk = w;
    const unsigned short* Wh = Whl;
    const unsigned short* Wl = Whl + 65536;
    const size_t xbase = (size_t)tile * 16 * 1028;

    int oct_w = l >> 1, off_w = (l & 1) * 4;

    f32x4 g[4];
#pragma unroll
    for (int p = 0; p < 4; p++)
        g[p] = *(const f32x4*)(x + xbase + (size_t)(p * 4 + w) * 1028 + l * 4);
#pragma unroll
    for (int p = 0; p < 4; p++) {
        int r = p * 4 + w;
        int op = r * 256 + (oct_w ^ (r & 7)) * 8 + off_w;
        s16x4 h4, l4;
#pragma unroll
        for (int i = 0; i < 4; i++) { short hi, lo; split2(g[p][i], hi, lo); h4[i] = hi; l4[i] = lo; }
        *(s16x4*)(&hib[0][op]) = h4;
        *(s16x4*)(&lob[0][op]) = l4;
    }
    __syncthreads();

    f32x4 acc = { 0.f, 0.f, 0.f, 0.f };
    for (int c = 0; c < 4; c++) {
        if (c < 3) {
#pragma unroll
            for (int p = 0; p < 4; p++)
                g[p] = *(const f32x4*)(x + xbase + (size_t)(p * 4 + w) * 1028 + (c + 1) * 256 + l * 4);
        }
        int buf = c & 1;
        const unsigned short* hp = &hib[buf][m * 256];
        const unsigned short* lp = &lob[buf][m * 256];
        int msw = m & 7;
#pragma unroll
        for (int ks = 0; ks < 8; ks++) {
            int oct = ks * 4 + quad;
            int ao = (oct ^ msw) * 8;
            bf16x8 xh = *(const bf16x8*)(hp + ao);
            bf16x8 xl = *(const bf16x8*)(lp + ao);
            int fb = (c * 8 + ks) * 2048 + blk * 512 + l * 8;
            bf16x8 bh = *(const bf16x8*)(Wh + fb);
            bf16x8 bl = *(const bf16x8*)(Wl + fb);
            acc = __builtin_amdgcn_mfma_f32_16x16x32_bf16(xh, bh, acc, 0, 0, 0);
            acc = __builtin_amdgcn_mfma_f32_16x16x32_bf16(xl, bh, acc, 0, 0, 0);
            acc = __builtin_amdgcn_mfma_f32_16x16x32_bf16(xh, bl, acc, 0, 0, 0);
        }
        if (c < 3) {
            int nbuf = (c + 1) & 1;
#pragma unroll
            for (int p = 0; p < 4; p++) {
                int r = p * 4 + w;
                int op = r * 256 + (oct_w ^ (r & 7)) * 8 + off_w;
                s16x4 h4, l4;
#pragma unroll
                for (int i = 0; i < 4; i++) { short hi, lo; split2(g[p][i], hi, lo); h4[i] = hi; l4[i] = lo; }
                *(s16x4*)(&hib[nbuf][op]) = h4;
                *(s16x4*)(&lob[nbuf][op]) = l4;
            }
            __syncthreads();
        }
    }

    int ch = blk * 16 + m;
    f32x4 wsp = *(const f32x4*)(WspP + ch * 4);
    float bia = bias01[ch];
#pragma unroll
    for (int r = 0; r < 4; r++) {
        int row = tile * 16 + quad * 4 + r;
        f32x4 sp = *(const f32x4*)(x + (size_t)row * 1028 + 1024);
        float a = acc[r] + sp[0] * wsp[0] + sp[1] * wsp[1]
                + sp[2] * wsp[2] + sp[3] * wsp[3] + bia;
        h[(size_t)row * 64 + ch] = fmaxf(a, 0.f);
    }
}

// ---------- K4: all 3 branches fused: P = h @ W1p' + b1 (f16), Q = h @ W1q' (f16) ----------
__global__ __launch_bounds__(256) void k_pq(
    const float* __restrict__ h, const float* __restrict__ WT3,
    const float* __restrict__ biasPQ, f16* __restrict__ Pi, f16* __restrict__ Qi)
{
    __shared__ float wt[64 * 128];
    __shared__ float xt[64 * 68];
    int tid = threadIdx.x;
    int m0 = blockIdx.x * 64;
    int cg = tid & 31, rg = tid >> 5;
#pragma unroll
    for (int i = 0; i < 4; i++) {
        int li = i * 256 + tid;
        int rr = li >> 4, q = li & 15;
        int row = m0 + rr;
        float4 u = make_float4(0.f, 0.f, 0.f, 0.f);
        if (row < NN) u = *(const float4*)(h + (size_t)row * 64 + q * 4);
        *(float4*)(xt + rr * 68 + q * 4) = u;
    }
    for (int b = 0; b < 3; b++) {
        __syncthreads();
#pragma unroll
        for (int i = 0; i < 8; i++)
            ((float4*)wt)[i * 256 + tid] = ((const float4*)(WT3 + b * 8192))[i * 256 + tid];
        __syncthreads();
        float acc[8][4];
#pragma unroll
        for (int r = 0; r < 8; r++)
#pragma unroll
            for (int j = 0; j < 4; j++) acc[r][j] = 0.f;
#pragma unroll 8
        for (int k = 0; k < 64; k++) {
            float4 wv = *(const float4*)(wt + k * 128 + cg * 4);
#pragma unroll
            for (int r = 0; r < 8; r++) {
                float xv = xt[(rg * 8 + r) * 68 + k];
                acc[r][0] += xv * wv.x; acc[r][1] += xv * wv.y;
                acc[r][2] += xv * wv.z; acc[r][3] += xv * wv.w;
            }
        }
        const float* biasP = biasPQ + b * 128;
#pragma unroll
        for (int r = 0; r < 8; r++) {
            int row = m0 + rg * 8 + r;
            if (row < NN) {
                if (cg < 16) {               // P half (+bias), fp16
                    f16x4 res;
#pragma unroll
                    for (int j = 0; j < 4; j++)
                        res[j] = (f16)(acc[r][j] + biasP[cg * 4 + j]);
                    *(f16x4*)(Pi + (size_t)row * 192 + b * 64 + cg * 4) = res;
                } else {                     // Q half, fp16
                    f16x4 res;
#pragma unroll
                    for (int j = 0; j < 4; j++)
                        res[j] = (f16)acc[r][j];
                    *(f16x4*)(Qi + (size_t)row * 192 + b * 64 + (cg - 16) * 4) = res;
                }
            }
        }
    }
}

// per-branch contiguous range: batches of 16, mask-free except tail row test.
#define ECV_BRANCH(B, EST, ECN)                                                    \
    {                                                                              \
        f16x8 pl = *(const f16x8*)(pr + (B) * 64 + quad * 8);                      \
        f16x8 ph = *(const f16x8*)(pr + (B) * 64 + 32 + quad * 8);                 \
        float acc[4][4];                                                           \
        _Pragma("unroll") for (int blk = 0; blk < 4; blk++)                        \
            _Pragma("unroll") for (int r = 0; r < 4; r++) acc[blk][r] = -3.0e38f;  \
        int nbF = (ECN) >> 4;                                                      \
        int rem = (ECN) & 15;                                                      \
        for (int bi = 0; bi < nbF; bi++) {                                         \
            int srcm = sorted[(EST) + bi * 16 + m] & 0xFFFF;                       \
            const f16* qr = Qi + (size_t)srcm * 192 + (B) * 64;                    \
            f16x8 q0 = *(const f16x8*)(qr + quad * 8);                             \
            f16x8 q1 = *(const f16x8*)(qr + 32 + quad * 8);                        \
            f16x8 a0 = relupq(pl, q0);                                             \
            f16x8 a1 = relupq(ph, q1);                                             \
            _Pragma("unroll") for (int blk = 0; blk < 4; blk++) {                  \
                f32x4 c = { 0.f, 0.f, 0.f, 0.f };                                  \
                f16x8 w0 = *(const f16x8*)(w2s + ((B) * 8 + blk * 2 + 0) * 512 + quad * 128 + m * 8); \
                f16x8 w1 = *(const f16x8*)(w2s + ((B) * 8 + blk * 2 + 1) * 512 + quad * 128 + m * 8); \
                c = __builtin_amdgcn_mfma_f32_16x16x32_f16(a0, w0, c, 0, 0, 0);    \
                c = __builtin_amdgcn_mfma_f32_16x16x32_f16(a1, w1, c, 0, 0, 0);    \
                _Pragma("unroll") for (int r = 0; r < 4; r++)                      \
                    acc[blk][r] = fmaxf(acc[blk][r], c[r]);                        \
            }                                                                      \
        }                                                                          \
        if (rem) {                                                                 \
            int e = (EST) + nbF * 16 + m;                                          \
            int srcm = sorted[(m < rem) ? e : (EST)] & 0xFFFF;                     \
            const f16* qr = Qi + (size_t)srcm * 192 + (B) * 64;                    \
            f16x8 q0 = *(const f16x8*)(qr + quad * 8);                             \
            f16x8 q1 = *(const f16x8*)(qr + 32 + quad * 8);                        \
            f16x8 a0 = relupq(pl, q0);                                             \
            f16x8 a1 = relupq(ph, q1);                                             \
            _Pragma("unroll") for (int blk = 0; blk < 4; blk++) {                  \
                f32x4 c = { 0.f, 0.f, 0.f, 0.f };                                  \
                f16x8 w0 = *(const f16x8*)(w2s + ((B) * 8 + blk * 2 + 0) * 512 + quad * 128 + m * 8); \
                f16x8 w1 = *(const f16x8*)(w2s + ((B) * 8 + blk * 2 + 1) * 512 + quad * 128 + m * 8); \
                c = __builtin_amdgcn_mfma_f32_16x16x32_f16(a0, w0, c, 0, 0, 0);    \
                c = __builtin_amdgcn_mfma_f32_16x16x32_f16(a1, w1, c, 0, 0, 0);    \
                _Pragma("unroll") for (int r = 0; r < 4; r++)                      \
                    if (quad * 4 + r < rem)                                        \
                        acc[blk][r] = fmaxf(acc[blk][r], c[r]);                    \
            }                                                                      \
        }                                                                          \
        float red[4];                                                              \
        _Pragma("unroll") for (int blk = 0; blk < 4; blk++) {                      \
            float rv = fmaxf(fmaxf(acc[blk][0], acc[blk][1]),                      \
                             fmaxf(acc[blk][2], acc[blk][3]));                     \
            rv = fmaxf(rv, __shfl_xor(rv, 16));                                    \
            rv = fmaxf(rv, __shfl_xor(rv, 32));                                    \
            red[blk] = rv;                                                         \
        }                                                                          \
        float mx = red[quad];                                                      \
        const float* scb = bnf + (B) * 192;                                        \
        float outv = ((ECN) > 0) ? fmaxf(fmaf(mx, scb[lane], scb[64 + lane]), 0.f) \
                                 : fmaxf(scb[128 + lane], 0.f);                    \
        y1i[(size_t)v * 192 + (B) * 64 + lane] = (f16)outv;                        \
    }

// ---------- K5: fused 3-branch EdgeConv; attr-sorted ranges; persistent waves ----------
__global__ __launch_bounds__(256) void k_edgeconv_f(
    const int* __restrict__ rowptr, const unsigned int* __restrict__ cnt01,
    const int* __restrict__ sorted,
    const f16* __restrict__ Pi, const f16* __restrict__ Qi,
    const f16* __restrict__ W2h,               // 3*64*64 f16
    const float* __restrict__ bnf,             // 3*192
    f16* __restrict__ y1i, float* __restrict__ invc4)
{
    __shared__ f16 w2s[12288];                 // 3 branches : 24 frags * 512 halves, bank-permuted
    int tid = threadIdx.x;
#pragma unroll
    for (int u0 = 0; u0 < 6; u0++) {
        int u = u0 * 256 + tid;                // 0..1535
        int frag = u >> 6;                     // b*8 + blk*2 + kc   (b in {0,1,2})
        int rem = u & 63;
        int m2 = rem >> 2, qd = rem & 3;
        int bb = frag >> 3, blk = (frag >> 1) & 3, kc = frag & 1;
        *(int4*)(w2s + frag * 512 + qd * 128 + m2 * 8) =
            *(const int4*)(W2h + (bb * 64 + blk * 16 + m2) * 64 + kc * 32 + qd * 8);
    }
    __syncthreads();

    int wid = tid >> 6, lane = tid & 63;
    int m = lane & 15, quad = lane >> 4;
    int gw = blockIdx.x * 4 + wid;             // persistent wave id, PW_EC total

    for (int v = gw; v < NN; v += PW_EC) {
        const f16* pr = Pi + (size_t)v * 192;
        int e0 = rowptr[v], e1 = rowptr[v + 1];
        int deg = e1 - e0;
        unsigned int cc = cnt01[v];
        int c0 = (int)(cc & 0xFFFFu);
        int c1 = (int)(cc >> 16);
        int n1cnt = deg - c0;                  // seg1 (a>=1): [e0+c0, e1)
        int n2cnt = c0 + c1;                   // seg2 (a<=1): [e0, e0+c0+c1)

        ECV_BRANCH(0, e0 + c0, n1cnt)
        ECV_BRANCH(1, e0, n2cnt)
        ECV_BRANCH(2, e0, deg)

        if (lane == 0) {
            float4 ic;
            ic.x = 1.f / (float)(n1cnt > 0 ? n1cnt : 1);
            ic.y = 1.f / (float)(n2cnt > 0 ? n2cnt : 1);
            ic.z = 1.f / (float)(deg   > 0 ? deg   : 1);
            ic.w = 0.f;
            *(float4*)(invc4 + (size_t)v * 4) = ic;
        }
    }
}

// per-branch range mean: 8 lanes/edge, unconditional f16x8 loads
#define AGG_BRANCH(B, EST, ECN, ICS)                                               \
    {                                                                              \
        float s[8];                                                                \
        _Pragma("unroll") for (int j = 0; j < 8; j++) s[j] = 0.f;                  \
        for (int eb = 0; eb < (ECN); eb += 8) {                                    \
            if (eb + eslot < (ECN)) {                                              \
                int src = sorted[(EST) + eb + eslot] & 0xFFFF;                     \
                f16x8 u = *(const f16x8*)(y1i + (size_t)src * 192 + (B) * 64 + cg * 8); \
                _Pragma("unroll") for (int j = 0; j < 8; j++) s[j] += (float)u[j]; \
            }                                                                      \
        }                                                                          \
        _Pragma("unroll") for (int j = 0; j < 8; j++) {                            \
            s[j] += __shfl_xor(s[j], 8);                                           \
            s[j] += __shfl_xor(s[j], 16);                                          \
            s[j] += __shfl_xor(s[j], 32);                                          \
        }                                                                          \
        if (eslot == 0) {                                                          \
            f16x8 r;                                                               \
            _Pragma("unroll") for (int j = 0; j < 8; j++) r[j] = (f16)(s[j] * (ICS)); \
            *(f16x8*)(aggi + (size_t)v * 192 + (B) * 64 + cg * 8) = r;             \
        }                                                                          \
    }

// ---------- K6a: fused 3-branch mean aggregation; attr-sorted ranges ----------
__global__ __launch_bounds__(256) void k_agg_f(
    const int* __restrict__ rowptr, const unsigned int* __restrict__ cnt01,
    const int* __restrict__ sorted,
    const f16* __restrict__ y1i, const float* __restrict__ invc4,
    f16* __restrict__ aggi)
{
    int wid = threadIdx.x >> 6, lane = threadIdx.x & 63;
    int eslot = lane >> 3, cg = lane & 7;
    int gw = blockIdx.x * 4 + wid;
    for (int v = gw; v < NN; v += PW_AG) {
        int e0 = rowptr[v], e1 = rowptr[v + 1];
        int deg = e1 - e0;
        unsigned int cc = cnt01[v];
        int c0 = (int)(cc & 0xFFFFu);
        int c1 = (int)(cc >> 16);
        float4 icv = *(const float4*)(invc4 + (size_t)v * 4);
        AGG_BRANCH(0, e0 + c0, deg - c0, icv.x)
        AGG_BRANCH(1, e0, c0 + c1, icv.y)
        AGG_BRANCH(2, e0, deg, icv.z)
    }
}

// ---------- K6b: sage1 + fused proj, MFMA; one 16-row tile per wave, 3 branches ----------
__global__ __launch_bounds__(256) void k_sage1(
    const f16* __restrict__ aggi, const f16* __restrict__ y1i,
    const f16* __restrict__ Wsg16,          // [64][128] f16, bn21-folded, shared across branches
    const float* __restrict__ bias21,
    const float* __restrict__ Wl0, const float* __restrict__ bl0, const float* __restrict__ Wr0,
    const float* __restrict__ Wl1, const float* __restrict__ bl1, const float* __restrict__ Wr1,
    const float* __restrict__ Wl2, const float* __restrict__ bl2, const float* __restrict__ Wr2,
    float* __restrict__ pz4)
{
    __shared__ f16 wsg[64 * SG_PAD];        // [col][k] padded
    int tid = threadIdx.x;
    for (int i = tid; i < 1024; i += 256) {
        int c = i >> 4, kq = i & 15;
        *(f16x8*)(wsg + c * SG_PAD + kq * 8) = *(const f16x8*)(Wsg16 + c * 128 + kq * 8);
    }
    __syncthreads();

    int wid = tid >> 6, lane = tid & 63;
    int m = lane & 15, quad = lane >> 4;
    int tile = blockIdx.x * 4 + wid;
    if (tile >= 3125) return;               // NN = 3125*16
    int rowm = tile * 16 + m;               // A-frag row for this lane
    int rowq = tile * 16 + quad * 4;        // C-rows base for this lane

    const float* Wlp[3] = { Wl0, Wl1, Wl2 };
    const float* Wrp[3] = { Wr0, Wr1, Wr2 };
    const float* blp[3] = { bl0, bl1, bl2 };

    float zsum[4] = { 0.f, 0.f, 0.f, 0.f };
#pragma unroll
    for (int b = 0; b < 3; b++) {
        const f16* ra = aggi + (size_t)rowm * 192 + b * 64 + quad * 8;
        const f16* ry = y1i  + (size_t)rowm * 192 + b * 64 + quad * 8;
        f16x8 a0 = *(const f16x8*)(ra);         // k 0..31   (agg)
        f16x8 a1 = *(const f16x8*)(ra + 32);    // k 32..63  (agg)
        f16x8 a2 = *(const f16x8*)(ry);         // k 64..95  (y1)
        f16x8 a3 = *(const f16x8*)(ry + 32);    // k 96..127 (y1)
        float ps[4] = { 0.f, 0.f, 0.f, 0.f };
        float zs[4] = { 0.f, 0.f, 0.f, 0.f };
#pragma unroll
        for (int cb = 0; cb < 4; cb++) {
            int col = cb * 16 + m;
            const f16* wb = wsg + col * SG_PAD + quad * 8;
            f32x4 acc = { 0.f, 0.f, 0.f, 0.f };
            acc = __builtin_amdgcn_mfma_f32_16x16x32_f16(a0, *(const f16x8*)(wb),      acc, 0, 0, 0);
            acc = __builtin_amdgcn_mfma_f32_16x16x32_f16(a1, *(const f16x8*)(wb + 32), acc, 0, 0, 0);
            acc = __builtin_amdgcn_mfma_f32_16x16x32_f16(a2, *(const f16x8*)(wb + 64), acc, 0, 0, 0);
            acc = __builtin_amdgcn_mfma_f32_16x16x32_f16(a3, *(const f16x8*)(wb + 96), acc, 0, 0, 0);
            float bz = bias21[col];
            float wlv = Wlp[b][col];
            float wrv = Wrp[b][col];
#pragma unroll
            for (int r = 0; r < 4; r++) {
                float y = fmaxf(acc[r] + bz, 0.f);
                ps[r] += y * wlv;
                zs[r] += y * wrv;
            }
        }
        float blv = blp[b][0];
#pragma unroll
        for (int r = 0; r < 4; r++) {
            ps[r] += __shfl_xor(ps[r], 1); ps[r] += __shfl_xor(ps[r], 2);
            ps[r] += __shfl_xor(ps[r], 4); ps[r] += __shfl_xor(ps[r], 8);
            zs[r] += __shfl_xor(zs[r], 1); zs[r] += __shfl_xor(zs[r], 2);
            zs[r] += __shfl_xor(zs[r], 4); zs[r] += __shfl_xor(zs[r], 8);
            zsum[r] += zs[r] + blv;
        }
        if (m == 0) {
#pragma unroll
            for (int r = 0; r < 4; r++)
                pz4[(size_t)(rowq + r) * 4 + b] = ps[r];
        }
    }
    if (m == 0) {
#pragma unroll
        for (int r = 0; r < 4; r++)
            pz4[(size_t)(rowq + r) * 4 + 3] = zsum[r];
    }
}

// ---------- K8: fused 3-branch sage2 + sigmoid; 16 lanes/node, persistent ----------
__global__ __launch_bounds__(256) void k_sage2_f(
    const int* __restrict__ rowptr, const int* __restrict__ sorted,
    const float* __restrict__ pz4, const float* __restrict__ invc4,
    float* __restrict__ outp)
{
    int wid = threadIdx.x >> 6, lane = threadIdx.x & 63;
    int sub = lane >> 4, sl = lane & 15;       // 4 sub-groups of 16 lanes per wave
    int gw = blockIdx.x * 4 + wid;
    for (int v = gw * 4 + sub; v < NN; v += PW_AG * 4) {
        int e0 = rowptr[v], e1 = rowptr[v + 1];
        float s1 = 0.f, s2 = 0.f, s3 = 0.f;
        for (int e = e0 + sl; e < e1; e += 16) {
            int w = sorted[e];
            int src = w & 0xFFFF, a = (w >> 16) & 3;
            float4 pz = *(const float4*)(pz4 + (size_t)src * 4);
            s3 += pz.z;
            if (a >= 1) s1 += pz.x;
            if (a <= 1) s2 += pz.y;
        }
#pragma unroll
        for (int off = 1; off < 16; off <<= 1) {
            s1 += __shfl_xor(s1, off);
            s2 += __shfl_xor(s2, off);
            s3 += __shfl_xor(s3, off);
        }
        if (sl == 0) {
            float4 icv = *(const float4*)(invc4 + (size_t)v * 4);
            float zsum = pz4[(size_t)v * 4 + 3];
            float val = s1 * icv.x + s2 * icv.y + s3 * icv.z + zsum;
            outp[v] = 1.f / (1.f + expf(-val));
        }
    }
}

// ---------- launch ----------
extern "C" void kernel_launch(void* const* d_in, const int* in_sizes, int n_in,
                              void* d_out, int out_size, void* d_ws, size_t ws_size,
                              hipStream_t stream)
{
    const float* x    = (const float*)d_in[0];
    const int* ei     = (const int*)d_in[1];
    const int* attr   = (const int*)d_in[2];
    const float* Wspf = (const float*)d_in[3];
    const float* bspf = (const float*)d_in[4];
    const float* W011 = (const float*)d_in[5];
    const float* b011 = (const float*)d_in[6];
    const float* W012 = (const float*)d_in[7];
    const float* b012 = (const float*)d_in[8];
    const float* bn01 = (const float*)d_in[9];
    const float* eW1[3] = { (const float*)d_in[10], (const float*)d_in[15], (const float*)d_in[20] };
    const float* eb1[3] = { (const float*)d_in[11], (const float*)d_in[16], (const float*)d_in[21] };
    const float* eW2[3] = { (const float*)d_in[12], (const float*)d_in[17], (const float*)d_in[22] };
    const float* eb2[3] = { (const float*)d_in[13], (const float*)d_in[18], (const float*)d_in[23] };
    const float* bn1[3] = { (const float*)d_in[14], (const float*)d_in[19], (const float*)d_in[24] };
    const float* s21Wl = (const float*)d_in[25];
    const float* s21bl = (const float*)d_in[26];
    const float* s21Wr = (const float*)d_in[27];
    const float* bn21  = (const float*)d_in[28];
    const float* s3Wl[3] = { (const float*)d_in[29], (const float*)d_in[32], (const float*)d_in[35] };
    const float* s3bl[3] = { (const float*)d_in[30], (const float*)d_in[33], (const float*)d_in[36] };
    const float* s3Wr[3] = { (const float*)d_in[31], (const float*)d_in[34], (const float*)d_in[37] };

    char* ws = (char*)d_ws;
    unsigned short* Whl = (unsigned short*)(ws + OFF_WHL);
    float* WspP   = (float*)(ws + OFF_WSPP);
    float* bias01 = (float*)(ws + OFF_BIAS01);
    float* W1pqT  = (float*)(ws + OFF_W1PQT);
    float* biasPQ = (float*)(ws + OFF_BIASPQ);
    f16*   Wsg16  = (f16*)(ws + OFF_WSAGET);
    float* bias21 = (float*)(ws + OFF_BIAS21);
    float* bnf    = (float*)(ws + OFF_BNF);
    f16*   W2h    = (f16*)(ws + OFF_W2BF);
    float* invc4  = (float*)(ws + OFF_INVC4);
    float* pz4    = (float*)(ws + OFF_PZ4);
    int*   rp     = (int*)(ws + OFF_RP);
    int*   parts  = (int*)(ws + OFF_PARTS);
    int*   deg    = (int*)(ws + OFF_DEG);
    unsigned int* cnt01 = (unsigned int*)(ws + OFF_CNT01);
    int*   ghead  = (int*)(ws + OFF_GHEAD);
    int*   sorted = (int*)(ws + OFF_SORT);
    unsigned int* ebuck = (unsigned int*)(ws + OFF_EBUCK);
    float* h      = (float*)(ws + OFF_H);
    f16*   Pi     = (f16*)(ws + OFF_PI);
    f16*   Qi     = (f16*)(ws + OFF_QI);
    f16*   y1i    = (f16*)(ws + OFF_Y1I);
    f16*   aggi   = (f16*)(ws + OFF_AGGI);   // overlays Pi (dead after edgeconv)

    hipMemsetAsync(ws + OFF_DEG, 0, 200064, stream);   // deg only (cnt01 fully written by bucketB)

    k_prep<<<689, 256, 0, stream>>>(
        Wspf, bspf, W011, b011, W012, b012, bn01,
        eW1[0], eb1[0], eb2[0], bn1[0],
        eW1[1], eb1[1], eb2[1], bn1[1],
        eW1[2], eb1[2], eb2[2], bn1[2],
        eW2[0], eW2[1], eW2[2],
        s21Wl, s21bl, s21Wr, bn21,
        Whl, WspP, bias01, W1pqT, biasPQ, Wsg16, bias21, bnf, W2h);

    k_hist<<<3907, 256, 0, stream>>>(ei + EE, deg);
    k_psum<<<NBK, 256, 0, stream>>>(deg, parts);
    k_pscan<<<1, 256, 0, stream>>>(parts, ghead);
    k_scanfix<<<NBK, 256, 0, stream>>>(deg, parts, rp);
    k_bucketA<<<245, 256, 0, stream>>>(ei, ei + EE, attr, ghead, ebuck);
    k_bucketB<<<NBK, 256, 0, stream>>>(rp, ebuck, sorted, cnt01);

    k_h<<<3125, 256, 0, stream>>>(x, Whl, WspP, bias01, h);

    k_pq<<<782, 256, 0, stream>>>(h, W1pqT, biasPQ, Pi, Qi);

    k_edgeconv_f<<<PW_EC / 4, 256, 0, stream>>>(rp, cnt01, sorted, Pi, Qi, W2h, bnf, y1i, invc4);
    k_agg_f<<<PW_AG / 4, 256, 0, stream>>>(rp, cnt01, sorted, y1i, invc4, aggi);

    k_sage1<<<782, 256, 0, stream>>>(aggi, y1i, Wsg16, bias21,
                                     s3Wl[0], s3bl[0], s3Wr[0],
                                     s3Wl[1], s3bl[1], s3Wr[1],
                                     s3Wl[2], s3bl[2], s3Wr[2], pz4);

    k_sage2_f<<<PW_AG / 4, 256, 0, stream>>>(rp, sorted, pz4, invc4, (float*)d_out);
}

// Round 12
// 684.734 us; speedup vs baseline: 1.1369x; 1.0389x over previous
//
#include <hip/hip_runtime.h>
#include <cstdint>
#include <cstddef>

#define NN 50000
#define EE 1000000
#define NBK 196          // dst buckets (dst>>8), 196*256 = 50176 >= NN
#define PW_EC 6144       // persistent waves, edgeconv (1536 blocks * 4; 6 blocks/CU LDS cap)
#define PW_AG 8192       // persistent waves, agg/sage2 (2048 blocks * 4)
#define SG_PAD 136       // Wsage LDS row pad (f16 units): 2-way bank aliasing = free

typedef __attribute__((ext_vector_type(8))) short bf16x8;
typedef __attribute__((ext_vector_type(4))) short s16x4;
typedef __attribute__((ext_vector_type(4))) float f32x4;
typedef _Float16 f16;
typedef __attribute__((ext_vector_type(2))) _Float16 f16x2;
typedef __attribute__((ext_vector_type(4))) _Float16 f16x4;
typedef __attribute__((ext_vector_type(8))) _Float16 f16x8;

// truncation split: v == bf16(hi) + ~bf16(lo), residual ~2^-16 rel
__device__ __forceinline__ void split2(float v, short& hi, short& lo) {
    union { float f; unsigned int u; } a; a.f = v;
    unsigned short h16 = (unsigned short)(a.u >> 16);
    union { unsigned int u; float f; } hf; hf.u = ((unsigned int)h16) << 16;
    union { float f; unsigned int u; } b; b.f = v - hf.f;
    hi = (short)h16;
    lo = (short)(b.u >> 16);
}

// relu(p+q) in packed f16 (v_pk_add_f16 + v_pk_max_f16)
__device__ __forceinline__ f16x8 relupq(f16x8 p, f16x8 q) {
    f16x8 s = p + q;
    f16x8 z = {};
#if __has_builtin(__builtin_elementwise_max)
    return __builtin_elementwise_max(s, z);
#else
    f16x8 r;
#pragma unroll
    for (int j = 0; j < 8; j++) r[j] = (s[j] > (f16)0.f) ? s[j] : (f16)0.f;
    return r;
#endif
}

// ---------- workspace layout (byte offsets) ----------
#define OFF_WHL    ((size_t)0)          // 2*1024*64 bf16 = 262144
#define OFF_WSPP   ((size_t)262144)     // 64*4 f32
#define OFF_BIAS01 ((size_t)263168)     // 64 f32
#define OFF_W1PQT  ((size_t)263424)     // 3*128*64 f16 = 49152 (B-layout [b][col][k])
#define OFF_BIASPQ ((size_t)361728)     // 3*128 f32
#define OFF_WSAGET ((size_t)363264)     // 64*128 f16 = 16384 (in 32KB slot)
#define OFF_BIAS21 ((size_t)396032)     // 64 f32
#define OFF_BNF    ((size_t)396288)     // 3*192 f32 (+pad to 2560)
#define OFF_W2BF   ((size_t)398848)     // 3*64*64 f16 = 24576
#define OFF_INVC4  ((size_t)423424)     // N*4 f32 = 800000 {ic1,ic2,ic3,0}
#define OFF_PZ4    ((size_t)1223424)    // N*4 f32 = 800000 {p1,p2,p3,zsum}
#define OFF_RP     ((size_t)2023424)    // (NN+1) i32 (+pad 200064)
#define OFF_PARTS  ((size_t)2223488)    // 256 i32 (+pad 4096)
#define OFF_DEG    ((size_t)2227584)    // N i32 (+pad 200064)
#define OFF_CNT01  ((size_t)2427648)    // N u32 (+pad 200064)  {c0 | c1<<16}, written by bucketB
#define OFF_GHEAD  ((size_t)2627712)    // NBK i32 (+pad 4096)
#define OFF_SORT   ((size_t)2631808)    // E i32 = 4000000 (src | attr<<16), attr-sorted within node
#define OFF_H      ((size_t)6631808)    // N*64 f16 = 6400000 (in 12.8MB slot)
#define OFF_PI     ((size_t)19431808)   // N*192 f16 = 19200000 (P, interleaved 3 branches)
#define OFF_QI     ((size_t)38631808)   // N*192 f16 = 19200000 (Q, interleaved)
#define OFF_Y1I    ((size_t)57831808)   // N*192 f16 = 19200000 (end 77031808)
#define OFF_EBUCK  OFF_H                // overlay: E u32, dead before k_h
#define OFF_AGGI   OFF_PI               // overlay: N*192 f16, Pi dead after edgeconv

// ---------- K1: weight prep / folding ----------
__global__ __launch_bounds__(256) void k_prep(
    const float* __restrict__ Wspf, const float* __restrict__ bspf,
    const float* __restrict__ W011, const float* __restrict__ b011,
    const float* __restrict__ W012, const float* __restrict__ b012,
    const float* __restrict__ bn01,
    const float* __restrict__ e1W1, const float* __restrict__ e1b1,
    const float* __restrict__ e1b2, const float* __restrict__ bn11,
    const float* __restrict__ e2W1, const float* __restrict__ e2b1,
    const float* __restrict__ e2b2, const float* __restrict__ bn12,
    const float* __restrict__ e3W1, const float* __restrict__ e3b1,
    const float* __restrict__ e3b2, const float* __restrict__ bn13,
    const float* __restrict__ e1W2, const float* __restrict__ e2W2,
    const float* __restrict__ e3W2,
    const float* __restrict__ s21Wl, const float* __restrict__ s21bl,
    const float* __restrict__ s21Wr, const float* __restrict__ bn21,
    unsigned short* __restrict__ Whl, float* __restrict__ WspP, float* __restrict__ bias01,
    f16* __restrict__ W1h, float* __restrict__ biasPQ,
    f16* __restrict__ Wsg16, float* __restrict__ bias21, float* __restrict__ bnf,
    f16* __restrict__ W2h)
{
    int idx = blockIdx.x * 256 + threadIdx.x;
    if (idx < 131072) {
        int hl = idx >> 16;
        int r = idx & 65535;
        int kchunk = r >> 11;
        int r2 = r & 2047;
        int blk = r2 >> 9;
        int r3 = r2 & 511;
        int lane = r3 >> 3;
        int j = r3 & 7;
        int n = lane & 15, quad = lane >> 4;
        int k = kchunk * 32 + quad * 8 + j;
        int c = blk * 16 + n;
        float s = bn01[c] * rsqrtf(bn01[192 + c] + 1e-5f);
        float w = ((k < 512) ? W012[c * 512 + k] : W011[c * 576 + (k - 512)]) * s;
        short hi, lo;
        split2(w, hi, lo);
        Whl[idx] = (unsigned short)(hl ? lo : hi);
    } else if (idx < 131072 + 24576) {
        int r = idx - 131072;
        int b = r >> 13; r &= 8191;
        int k = r >> 7, cp = r & 127;
        const float* W1 = (b == 0) ? e1W1 : (b == 1) ? e2W1 : e3W1;
        float val;
        if (cp < 64) val = W1[cp * 128 + k] - W1[cp * 128 + 64 + k];
        else         val = W1[(cp - 64) * 128 + 64 + k];
        W1h[b * 8192 + cp * 64 + k] = (f16)val;   // B-layout [b][col][k]
    } else if (idx < 131072 + 24576 + 8192) {
        int r = idx - (131072 + 24576);
        int k = r >> 6, c = r & 63;
        float s = bn21[c] * rsqrtf(bn21[192 + c] + 1e-5f);
        float w = (k < 64) ? s21Wl[c * 64 + k] : s21Wr[c * 64 + (k - 64)];
        Wsg16[c * 128 + k] = (f16)(w * s);
    } else if (idx < 131072 + 24576 + 8192 + 64) {
        int c = idx - (131072 + 24576 + 8192);
        float s01 = bn01[c] * rsqrtf(bn01[192 + c] + 1e-5f);
        float wsp0 = 0.f, wsp1 = 0.f, wsp2 = 0.f, wsp3 = 0.f, bacc = 0.f;
        for (int j = 0; j < 64; j++) {
            float w = W011[c * 576 + 512 + j];
            wsp0 += w * Wspf[j * 4 + 0];
            wsp1 += w * Wspf[j * 4 + 1];
            wsp2 += w * Wspf[j * 4 + 2];
            wsp3 += w * Wspf[j * 4 + 3];
            bacc += w * bspf[j];
        }
        WspP[c * 4 + 0] = wsp0 * s01; WspP[c * 4 + 1] = wsp1 * s01;
        WspP[c * 4 + 2] = wsp2 * s01; WspP[c * 4 + 3] = wsp3 * s01;
        bias01[c] = (b011[c] + b012[c] + bacc) * s01 + (bn01[64 + c] - bn01[128 + c] * s01);
        float s21 = bn21[c] * rsqrtf(bn21[192 + c] + 1e-5f);
        bias21[c] = s21bl[c] * s21 + (bn21[64 + c] - bn21[128 + c] * s21);
        const float* b1a[3] = { e1b1, e2b1, e3b1 };
        const float* b2a[3] = { e1b2, e2b2, e3b2 };
        const float* bna[3] = { bn11, bn12, bn13 };
#pragma unroll
        for (int b = 0; b < 3; b++) {
            float s = bna[b][c] * rsqrtf(bna[b][192 + c] + 1e-5f);
            float tr = bna[b][64 + c] - bna[b][128 + c] * s;
            bnf[b * 192 + c] = s;
            bnf[b * 192 + 64 + c] = b2a[b][c] * s + tr;
            bnf[b * 192 + 128 + c] = tr;
            biasPQ[b * 128 + c] = b1a[b][c];
            biasPQ[b * 128 + 64 + c] = 0.f;
        }
    } else if (idx < 131072 + 24576 + 8192 + 64 + 12288) {
        int r = idx - (131072 + 24576 + 8192 + 64);
        int b = r >> 12, i = r & 4095;
        const float* W2 = (b == 0) ? e1W2 : (b == 1) ? e2W2 : e3W2;
        W2h[b * 4096 + i] = (f16)W2[i];
    }
}

// ---------- degree histogram (deg only; class counts come from bucketB) ----------
__global__ __launch_bounds__(256) void k_hist(
    const int* __restrict__ dst, int* __restrict__ deg)
{
    int e = blockIdx.x * 256 + threadIdx.x;
    if (e < EE) atomicAdd(&deg[dst[e]], 1);
}

__global__ __launch_bounds__(256) void k_psum(const int* __restrict__ deg, int* __restrict__ parts)
{
    int i = blockIdx.x * 256 + threadIdx.x;
    int v = (i < NN) ? deg[i] : 0;
#pragma unroll
    for (int off = 32; off > 0; off >>= 1) v += __shfl_xor(v, off);
    __shared__ int ws4[4];
    int wid = threadIdx.x >> 6;
    if ((threadIdx.x & 63) == 0) ws4[wid] = v;
    __syncthreads();
    if (threadIdx.x == 0)
        parts[blockIdx.x] = ws4[0] + ws4[1] + ws4[2] + ws4[3];
}

// exclusive scan of bucket counts; also emits ghead (= bucket base = rp[b*256])
__global__ __launch_bounds__(256) void k_pscan(int* __restrict__ parts, int* __restrict__ ghead)
{
    __shared__ int sbuf[256];
    int tid = threadIdx.x;
    int v = (tid < NBK) ? parts[tid] : 0;
    sbuf[tid] = v;
    __syncthreads();
    for (int off = 1; off < 256; off <<= 1) {
        int t = (tid >= off) ? sbuf[tid - off] : 0;
        __syncthreads();
        sbuf[tid] += t;
        __syncthreads();
    }
    if (tid < NBK) {
        int ex = sbuf[tid] - v;
        parts[tid] = ex;
        ghead[tid] = ex;
    }
}

__global__ __launch_bounds__(256) void k_scanfix(
    const int* __restrict__ deg, const int* __restrict__ parts, int* __restrict__ rowptr)
{
    __shared__ int sbuf[256];
    int tid = threadIdx.x;
    int i = blockIdx.x * 256 + tid;
    int v = (i < NN) ? deg[i] : 0;
    sbuf[tid] = v;
    __syncthreads();
    for (int off = 1; off < 256; off <<= 1) {
        int t = (tid >= off) ? sbuf[tid - off] : 0;
        __syncthreads();
        sbuf[tid] += t;
        __syncthreads();
    }
    int base = parts[blockIdx.x];
    if (i < NN)      rowptr[i] = base + sbuf[tid] - v;
    if (i == NN - 1) rowptr[NN] = base + sbuf[tid];
}

// ---------- bucketed sort pass A: partition edges into dst-buckets ----------
__global__ __launch_bounds__(256) void k_bucketA(
    const int* __restrict__ src, const int* __restrict__ dst, const int* __restrict__ attr,
    int* __restrict__ ghead, unsigned int* __restrict__ ebuck)
{
    __shared__ int hist[NBK];
    __shared__ int head[NBK];
    int tid = threadIdx.x;
    if (tid < NBK) hist[tid] = 0;
    __syncthreads();
    int base_e = blockIdx.x * 4096;
    unsigned int word[16]; int bkt[16];
#pragma unroll
    for (int k = 0; k < 16; k++) {
        int e = base_e + k * 256 + tid;
        if (e < EE) {
            int d = dst[e], s = src[e], a = attr[e] + 1;
            int b = d >> 8;
            word[k] = (unsigned)s | ((unsigned)a << 16) | ((unsigned)(d & 255) << 18);
            bkt[k] = b;
            atomicAdd(&hist[b], 1);
        } else { bkt[k] = -1; word[k] = 0; }
    }
    __syncthreads();
    if (tid < NBK) {
        int c = hist[tid];
        head[tid] = c ? atomicAdd(&ghead[tid], c) : 0;
    }
    __syncthreads();
#pragma unroll
    for (int k = 0; k < 16; k++) {
        if (bkt[k] >= 0) {
            int pos = atomicAdd(&head[bkt[k]], 1);
            ebuck[pos] = word[k];
        }
    }
}

// ---------- bucketed sort pass B: sort by (dst&255, attr); emits cnt01 for free ----------
__global__ __launch_bounds__(256) void k_bucketB(
    const int* __restrict__ rp, const unsigned int* __restrict__ ebuck,
    int* __restrict__ sorted, unsigned int* __restrict__ cnt01)
{
    __shared__ int sbuf[1024];
    __shared__ int head[1024];
    __shared__ int s2[256];
    int b = blockIdx.x, tid = threadIdx.x;
    int n0 = b * 256;
    int n1 = n0 + 256; if (n1 > NN) n1 = NN;
    int r0 = rp[n0];
    int r1 = rp[n1];
    for (int i = tid; i < 1024; i += 256) sbuf[i] = 0;
    __syncthreads();
    for (int e = r0 + tid; e < r1; e += 256)
        atomicAdd(&sbuf[(ebuck[e] >> 16) & 1023], 1);    // key = (d&255)*4 + a
    __syncthreads();
    int i0 = tid * 4;                                    // thread tid owns node n0+tid
    int v0 = sbuf[i0], v1 = sbuf[i0 + 1], v2 = sbuf[i0 + 2], v3 = sbuf[i0 + 3];
    if (n0 + tid < NN)
        cnt01[n0 + tid] = (unsigned)v0 | ((unsigned)v1 << 16);
    int tot = v0 + v1 + v2 + v3;
    s2[tid] = tot;
    __syncthreads();
    for (int off = 1; off < 256; off <<= 1) {
        int t = (tid >= off) ? s2[tid - off] : 0;
        __syncthreads();
        s2[tid] += t;
        __syncthreads();
    }
    int ex = s2[tid] - tot;
    head[i0]     = r0 + ex;
    head[i0 + 1] = r0 + ex + v0;
    head[i0 + 2] = r0 + ex + v0 + v1;
    head[i0 + 3] = r0 + ex + v0 + v1 + v2;
    __syncthreads();
    for (int e = r0 + tid; e < r1; e += 256) {
        unsigned int w = ebuck[e];
        int pos = atomicAdd(&head[(w >> 16) & 1023], 1);
        sorted[pos] = (int)(w & 0x3FFFFu);   // src | attr<<16
    }
}

// ---------- K2: h = relu(fold_bn01(x @ Wc')) ; h stored f16 ----------
__global__ __launch_bounds__(256) void k_h(
    const float* __restrict__ x, const unsigned short* __restrict__ Whl,
    const float* __restrict__ WspP, const float* __restrict__ bias01,
    f16* __restrict__ h)
{
    __shared__ unsigned short hib[2][4096];
    __shared__ unsigned short lob[2][4096];
    int tid = threadIdx.x;
    int w = tid >> 6, l = tid & 63;
    int tile = blockIdx.x;
    int m = l & 15, quad = l >> 4;
    int blk = w;
    const unsigned short* Wh = Whl;
    const unsigned short* Wl = Whl + 65536;
    const size_t xbase = (size_t)tile * 16 * 1028;

    int oct_w = l >> 1, off_w = (l & 1) * 4;

    f32x4 g[4];
#pragma unroll
    for (int p = 0; p < 4; p++)
        g[p] = *(const f32x4*)(x + xbase + (size_t)(p * 4 + w) * 1028 + l * 4);
#pragma unroll
    for (int p = 0; p < 4; p++) {
        int r = p * 4 + w;
        int op = r * 256 + (oct_w ^ (r & 7)) * 8 + off_w;
        s16x4 h4, l4;
#pragma unroll
        for (int i = 0; i < 4; i++) { short hi, lo; split2(g[p][i], hi, lo); h4[i] = hi; l4[i] = lo; }
        *(s16x4*)(&hib[0][op]) = h4;
        *(s16x4*)(&lob[0][op]) = l4;
    }
    __syncthreads();

    f32x4 acc = { 0.f, 0.f, 0.f, 0.f };
    for (int c = 0; c < 4; c++) {
        if (c < 3) {
#pragma unroll
            for (int p = 0; p < 4; p++)
                g[p] = *(const f32x4*)(x + xbase + (size_t)(p * 4 + w) * 1028 + (c + 1) * 256 + l * 4);
        }
        int buf = c & 1;
        const unsigned short* hp = &hib[buf][m * 256];
        const unsigned short* lp = &lob[buf][m * 256];
        int msw = m & 7;
#pragma unroll
        for (int ks = 0; ks < 8; ks++) {
            int oct = ks * 4 + quad;
            int ao = (oct ^ msw) * 8;
            bf16x8 xh = *(const bf16x8*)(hp + ao);
            bf16x8 xl = *(const bf16x8*)(lp + ao);
            int fb = (c * 8 + ks) * 2048 + blk * 512 + l * 8;
            bf16x8 bh = *(const bf16x8*)(Wh + fb);
            bf16x8 bl = *(const bf16x8*)(Wl + fb);
            acc = __builtin_amdgcn_mfma_f32_16x16x32_bf16(xh, bh, acc, 0, 0, 0);
            acc = __builtin_amdgcn_mfma_f32_16x16x32_bf16(xl, bh, acc, 0, 0, 0);
            acc = __builtin_amdgcn_mfma_f32_16x16x32_bf16(xh, bl, acc, 0, 0, 0);
        }
        if (c < 3) {
            int nbuf = (c + 1) & 1;
#pragma unroll
            for (int p = 0; p < 4; p++) {
                int r = p * 4 + w;
                int op = r * 256 + (oct_w ^ (r & 7)) * 8 + off_w;
                s16x4 h4, l4;
#pragma unroll
                for (int i = 0; i < 4; i++) { short hi, lo; split2(g[p][i], hi, lo); h4[i] = hi; l4[i] = lo; }
                *(s16x4*)(&hib[nbuf][op]) = h4;
                *(s16x4*)(&lob[nbuf][op]) = l4;
            }
            __syncthreads();
        }
    }

    int ch = blk * 16 + m;
    f32x4 wsp = *(const f32x4*)(WspP + ch * 4);
    float bia = bias01[ch];
#pragma unroll
    for (int r = 0; r < 4; r++) {
        int row = tile * 16 + quad * 4 + r;
        f32x4 sp = *(const f32x4*)(x + (size_t)row * 1028 + 1024);
        float a = acc[r] + sp[0] * wsp[0] + sp[1] * wsp[1]
                + sp[2] * wsp[2] + sp[3] * wsp[3] + bia;
        h[(size_t)row * 64 + ch] = (f16)fmaxf(a, 0.f);
    }
}

// ---------- K4: MFMA P/Q: per 16-row tile, 3 branches; W1h [b][col][k] from L2 ----------
__global__ __launch_bounds__(256) void k_pq(
    const f16* __restrict__ h, const f16* __restrict__ W1h,
    const float* __restrict__ biasPQ, f16* __restrict__ Pi, f16* __restrict__ Qi)
{
    int tid = threadIdx.x;
    int wid = tid >> 6, lane = tid & 63;
    int m = lane & 15, quad = lane >> 4;
    int tile = blockIdx.x * 4 + wid;
    if (tile >= 3125) return;               // NN = 3125*16
    int rowm = tile * 16 + m;
    int rowq = tile * 16 + quad * 4;

    const f16* hr = h + (size_t)rowm * 64 + quad * 8;
    f16x8 a0 = *(const f16x8*)(hr);         // k 0..31 slice
    f16x8 a1 = *(const f16x8*)(hr + 32);    // k 32..63 slice

#pragma unroll
    for (int b = 0; b < 3; b++) {
        const f16* wb0 = W1h + b * 8192;
#pragma unroll
        for (int cb = 0; cb < 8; cb++) {
            int col = cb * 16 + m;
            const f16* wbp = wb0 + col * 64 + quad * 8;
            f32x4 acc = { 0.f, 0.f, 0.f, 0.f };
            acc = __builtin_amdgcn_mfma_f32_16x16x32_f16(a0, *(const f16x8*)(wbp),      acc, 0, 0, 0);
            acc = __builtin_amdgcn_mfma_f32_16x16x32_f16(a1, *(const f16x8*)(wbp + 32), acc, 0, 0, 0);
            if (cb < 4) {                   // P half (+bias)
                float bz = biasPQ[b * 128 + col];
#pragma unroll
                for (int r = 0; r < 4; r++)
                    Pi[(size_t)(rowq + r) * 192 + b * 64 + col] = (f16)(acc[r] + bz);
            } else {                        // Q half
#pragma unroll
                for (int r = 0; r < 4; r++)
                    Qi[(size_t)(rowq + r) * 192 + b * 64 + (col - 64)] = (f16)acc[r];
            }
        }
    }
}

// per-branch contiguous range: batches of 16, mask-free except tail row test.
#define ECV_BRANCH(B, EST, ECN)                                                    \
    {                                                                              \
        f16x8 pl = *(const f16x8*)(pr + (B) * 64 + quad * 8);                      \
        f16x8 ph = *(const f16x8*)(pr + (B) * 64 + 32 + quad * 8);                 \
        float acc[4][4];                                                           \
        _Pragma("unroll") for (int blk = 0; blk < 4; blk++)                        \
            _Pragma("unroll") for (int r = 0; r < 4; r++) acc[blk][r] = -3.0e38f;  \
        int nbF = (ECN) >> 4;                                                      \
        int rem = (ECN) & 15;                                                      \
        for (int bi = 0; bi < nbF; bi++) {                                         \
            int srcm = sorted[(EST) + bi * 16 + m] & 0xFFFF;                       \
            const f16* qr = Qi + (size_t)srcm * 192 + (B) * 64;                    \
            f16x8 q0 = *(const f16x8*)(qr + quad * 8);                             \
            f16x8 q1 = *(const f16x8*)(qr + 32 + quad * 8);                        \
            f16x8 a0 = relupq(pl, q0);                                             \
            f16x8 a1 = relupq(ph, q1);                                             \
            _Pragma("unroll") for (int blk = 0; blk < 4; blk++) {                  \
                f32x4 c = { 0.f, 0.f, 0.f, 0.f };                                  \
                f16x8 w0 = *(const f16x8*)(w2s + ((B) * 8 + blk * 2 + 0) * 512 + quad * 128 + m * 8); \
                f16x8 w1 = *(const f16x8*)(w2s + ((B) * 8 + blk * 2 + 1) * 512 + quad * 128 + m * 8); \
                c = __builtin_amdgcn_mfma_f32_16x16x32_f16(a0, w0, c, 0, 0, 0);    \
                c = __builtin_amdgcn_mfma_f32_16x16x32_f16(a1, w1, c, 0, 0, 0);    \
                _Pragma("unroll") for (int r = 0; r < 4; r++)                      \
                    acc[blk][r] = fmaxf(acc[blk][r], c[r]);                        \
            }                                                                      \
        }                                                                          \
        if (rem) {                                                                 \
            int e = (EST) + nbF * 16 + m;                                          \
            int srcm = sorted[(m < rem) ? e : (EST)] & 0xFFFF;                     \
            const f16* qr = Qi + (size_t)srcm * 192 + (B) * 64;                    \
            f16x8 q0 = *(const f16x8*)(qr + quad * 8);                             \
            f16x8 q1 = *(const f16x8*)(qr + 32 + quad * 8);                        \
            f16x8 a0 = relupq(pl, q0);                                             \
            f16x8 a1 = relupq(ph, q1);                                             \
            _Pragma("unroll") for (int blk = 0; blk < 4; blk++) {                  \
                f32x4 c = { 0.f, 0.f, 0.f, 0.f };                                  \
                f16x8 w0 = *(const f16x8*)(w2s + ((B) * 8 + blk * 2 + 0) * 512 + quad * 128 + m * 8); \
                f16x8 w1 = *(const f16x8*)(w2s + ((B) * 8 + blk * 2 + 1) * 512 + quad * 128 + m * 8); \
                c = __builtin_amdgcn_mfma_f32_16x16x32_f16(a0, w0, c, 0, 0, 0);    \
                c = __builtin_amdgcn_mfma_f32_16x16x32_f16(a1, w1, c, 0, 0, 0);    \
                _Pragma("unroll") for (int r = 0; r < 4; r++)                      \
                    if (quad * 4 + r < rem)                                        \
                        acc[blk][r] = fmaxf(acc[blk][r], c[r]);                    \
            }                                                                      \
        }                                                                          \
        float red[4];                                                              \
        _Pragma("unroll") for (int blk = 0; blk < 4; blk++) {                      \
            float rv = fmaxf(fmaxf(acc[blk][0], acc[blk][1]),                      \
                             fmaxf(acc[blk][2], acc[blk][3]));                     \
            rv = fmaxf(rv, __shfl_xor(rv, 16));                                    \
            rv = fmaxf(rv, __shfl_xor(rv, 32));                                    \
            red[blk] = rv;                                                         \
        }                                                                          \
        float mx = red[quad];                                                      \
        const float* scb = bnf + (B) * 192;                                        \
        float outv = ((ECN) > 0) ? fmaxf(fmaf(mx, scb[lane], scb[64 + lane]), 0.f) \
                                 : fmaxf(scb[128 + lane], 0.f);                    \
        y1i[(size_t)v * 192 + (B) * 64 + lane] = (f16)outv;                        \
    }

// ---------- K5: fused 3-branch EdgeConv; attr-sorted ranges; persistent waves ----------
__global__ __launch_bounds__(256) void k_edgeconv_f(
    const int* __restrict__ rowptr, const unsigned int* __restrict__ cnt01,
    const int* __restrict__ sorted,
    const f16* __restrict__ Pi, const f16* __restrict__ Qi,
    const f16* __restrict__ W2h,               // 3*64*64 f16
    const float* __restrict__ bnf,             // 3*192
    f16* __restrict__ y1i, float* __restrict__ invc4)
{
    __shared__ f16 w2s[12288];                 // 3 branches : 24 frags * 512 halves, bank-permuted
    int tid = threadIdx.x;
#pragma unroll
    for (int u0 = 0; u0 < 6; u0++) {
        int u = u0 * 256 + tid;                // 0..1535
        int frag = u >> 6;                     // b*8 + blk*2 + kc   (b in {0,1,2})
        int rem = u & 63;
        int m2 = rem >> 2, qd = rem & 3;
        int bb = frag >> 3, blk = (frag >> 1) & 3, kc = frag & 1;
        *(int4*)(w2s + frag * 512 + qd * 128 + m2 * 8) =
            *(const int4*)(W2h + (bb * 64 + blk * 16 + m2) * 64 + kc * 32 + qd * 8);
    }
    __syncthreads();

    int wid = tid >> 6, lane = tid & 63;
    int m = lane & 15, quad = lane >> 4;
    int gw = blockIdx.x * 4 + wid;             // persistent wave id, PW_EC total

    for (int v = gw; v < NN; v += PW_EC) {
        const f16* pr = Pi + (size_t)v * 192;
        int e0 = rowptr[v], e1 = rowptr[v + 1];
        int deg = e1 - e0;
        unsigned int cc = cnt01[v];
        int c0 = (int)(cc & 0xFFFFu);
        int c1 = (int)(cc >> 16);
        int n1cnt = deg - c0;                  // seg1 (a>=1): [e0+c0, e1)
        int n2cnt = c0 + c1;                   // seg2 (a<=1): [e0, e0+c0+c1)

        ECV_BRANCH(0, e0 + c0, n1cnt)
        ECV_BRANCH(1, e0, n2cnt)
        ECV_BRANCH(2, e0, deg)

        if (lane == 0) {
            float4 ic;
            ic.x = 1.f / (float)(n1cnt > 0 ? n1cnt : 1);
            ic.y = 1.f / (float)(n2cnt > 0 ? n2cnt : 1);
            ic.z = 1.f / (float)(deg   > 0 ? deg   : 1);
            ic.w = 0.f;
            *(float4*)(invc4 + (size_t)v * 4) = ic;
        }
    }
}

// per-branch range mean: 8 lanes/edge, unconditional f16x8 loads
#define AGG_BRANCH(B, EST, ECN, ICS)                                               \
    {                                                                              \
        float s[8];                                                                \
        _Pragma("unroll") for (int j = 0; j < 8; j++) s[j] = 0.f;                  \
        for (int eb = 0; eb < (ECN); eb += 8) {                                    \
            if (eb + eslot < (ECN)) {                                              \
                int src = sorted[(EST) + eb + eslot] & 0xFFFF;                     \
                f16x8 u = *(const f16x8*)(y1i + (size_t)src * 192 + (B) * 64 + cg * 8); \
                _Pragma("unroll") for (int j = 0; j < 8; j++) s[j] += (float)u[j]; \
            }                                                                      \
        }                                                                          \
        _Pragma("unroll") for (int j = 0; j < 8; j++) {                            \
            s[j] += __shfl_xor(s[j], 8);                                           \
            s[j] += __shfl_xor(s[j], 16);                                          \
            s[j] += __shfl_xor(s[j], 32);                                          \
        }                                                                          \
        if (eslot == 0) {                                                          \
            f16x8 r;                                                               \
            _Pragma("unroll") for (int j = 0; j < 8; j++) r[j] = (f16)(s[j] * (ICS)); \
            *(f16x8*)(aggi + (size_t)v * 192 + (B) * 64 + cg * 8) = r;             \
        }                                                                          \
    }

// ---------- K6a: fused 3-branch mean aggregation; attr-sorted ranges ----------
__global__ __launch_bounds__(256) void k_agg_f(
    const int* __restrict__ rowptr, const unsigned int* __restrict__ cnt01,
    const int* __restrict__ sorted,
    const f16* __restrict__ y1i, const float* __restrict__ invc4,
    f16* __restrict__ aggi)
{
    int wid = threadIdx.x >> 6, lane = threadIdx.x & 63;
    int eslot = lane >> 3, cg = lane & 7;
    int gw = blockIdx.x * 4 + wid;
    for (int v = gw; v < NN; v += PW_AG) {
        int e0 = rowptr[v], e1 = rowptr[v + 1];
        int deg = e1 - e0;
        unsigned int cc = cnt01[v];
        int c0 = (int)(cc & 0xFFFFu);
        int c1 = (int)(cc >> 16);
        float4 icv = *(const float4*)(invc4 + (size_t)v * 4);
        AGG_BRANCH(0, e0 + c0, deg - c0, icv.x)
        AGG_BRANCH(1, e0, c0 + c1, icv.y)
        AGG_BRANCH(2, e0, deg, icv.z)
    }
}

// ---------- K6b: sage1 + fused proj, MFMA; one 16-row tile per wave, 3 branches ----------
__global__ __launch_bounds__(256) void k_sage1(
    const f16* __restrict__ aggi, const f16* __restrict__ y1i,
    const f16* __restrict__ Wsg16,          // [64][128] f16, bn21-folded, shared across branches
    const float* __restrict__ bias21,
    const float* __restrict__ Wl0, const float* __restrict__ bl0, const float* __restrict__ Wr0,
    const float* __restrict__ Wl1, const float* __restrict__ bl1, const float* __restrict__ Wr1,
    const float* __restrict__ Wl2, const float* __restrict__ bl2, const float* __restrict__ Wr2,
    float* __restrict__ pz4)
{
    __shared__ f16 wsg[64 * SG_PAD];        // [col][k] padded
    int tid = threadIdx.x;
    for (int i = tid; i < 1024; i += 256) {
        int c = i >> 4, kq = i & 15;
        *(f16x8*)(wsg + c * SG_PAD + kq * 8) = *(const f16x8*)(Wsg16 + c * 128 + kq * 8);
    }
    __syncthreads();

    int wid = tid >> 6, lane = tid & 63;
    int m = lane & 15, quad = lane >> 4;
    int tile = blockIdx.x * 4 + wid;
    if (tile >= 3125) return;               // NN = 3125*16
    int rowm = tile * 16 + m;               // A-frag row for this lane
    int rowq = tile * 16 + quad * 4;        // C-rows base for this lane

    const float* Wlp[3] = { Wl0, Wl1, Wl2 };
    const float* Wrp[3] = { Wr0, Wr1, Wr2 };
    const float* blp[3] = { bl0, bl1, bl2 };

    float zsum[4] = { 0.f, 0.f, 0.f, 0.f };
#pragma unroll
    for (int b = 0; b < 3; b++) {
        const f16* ra = aggi + (size_t)rowm * 192 + b * 64 + quad * 8;
        const f16* ry = y1i  + (size_t)rowm * 192 + b * 64 + quad * 8;
        f16x8 a0 = *(const f16x8*)(ra);         // k 0..31   (agg)
        f16x8 a1 = *(const f16x8*)(ra + 32);    // k 32..63  (agg)
        f16x8 a2 = *(const f16x8*)(ry);         // k 64..95  (y1)
        f16x8 a3 = *(const f16x8*)(ry + 32);    // k 96..127 (y1)
        float ps[4] = { 0.f, 0.f, 0.f, 0.f };
        float zs[4] = { 0.f, 0.f, 0.f, 0.f };
#pragma unroll
        for (int cb = 0; cb < 4; cb++) {
            int col = cb * 16 + m;
            const f16* wb = wsg + col * SG_PAD + quad * 8;
            f32x4 acc = { 0.f, 0.f, 0.f, 0.f };
            acc = __builtin_amdgcn_mfma_f32_16x16x32_f16(a0, *(const f16x8*)(wb),      acc, 0, 0, 0);
            acc = __builtin_amdgcn_mfma_f32_16x16x32_f16(a1, *(const f16x8*)(wb + 32), acc, 0, 0, 0);
            acc = __builtin_amdgcn_mfma_f32_16x16x32_f16(a2, *(const f16x8*)(wb + 64), acc, 0, 0, 0);
            acc = __builtin_amdgcn_mfma_f32_16x16x32_f16(a3, *(const f16x8*)(wb + 96), acc, 0, 0, 0);
            float bz = bias21[col];
            float wlv = Wlp[b][col];
            float wrv = Wrp[b][col];
#pragma unroll
            for (int r = 0; r < 4; r++) {
                float y = fmaxf(acc[r] + bz, 0.f);
                ps[r] += y * wlv;
                zs[r] += y * wrv;
            }
        }
        float blv = blp[b][0];
#pragma unroll
        for (int r = 0; r < 4; r++) {
            ps[r] += __shfl_xor(ps[r], 1); ps[r] += __shfl_xor(ps[r], 2);
            ps[r] += __shfl_xor(ps[r], 4); ps[r] += __shfl_xor(ps[r], 8);
            zs[r] += __shfl_xor(zs[r], 1); zs[r] += __shfl_xor(zs[r], 2);
            zs[r] += __shfl_xor(zs[r], 4); zs[r] += __shfl_xor(zs[r], 8);
            zsum[r] += zs[r] + blv;
        }
        if (m == 0) {
#pragma unroll
            for (int r = 0; r < 4; r++)
                pz4[(size_t)(rowq + r) * 4 + b] = ps[r];
        }
    }
    if (m == 0) {
#pragma unroll
        for (int r = 0; r < 4; r++)
            pz4[(size_t)(rowq + r) * 4 + 3] = zsum[r];
    }
}

// ---------- K8: fused 3-branch sage2 + sigmoid; 16 lanes/node, persistent ----------
__global__ __launch_bounds__(256) void k_sage2_f(
    const int* __restrict__ rowptr, const int* __restrict__ sorted,
    const float* __restrict__ pz4, const float* __restrict__ invc4,
    float* __restrict__ outp)
{
    int wid = threadIdx.x >> 6, lane = threadIdx.x & 63;
    int sub = lane >> 4, sl = lane & 15;       // 4 sub-groups of 16 lanes per wave
    int gw = blockIdx.x * 4 + wid;
    for (int v = gw * 4 + sub; v < NN; v += PW_AG * 4) {
        int e0 = rowptr[v], e1 = rowptr[v + 1];
        float s1 = 0.f, s2 = 0.f, s3 = 0.f;
        for (int e = e0 + sl; e < e1; e += 16) {
            int w = sorted[e];
            int src = w & 0xFFFF, a = (w >> 16) & 3;
            float4 pz = *(const float4*)(pz4 + (size_t)src * 4);
            s3 += pz.z;
            if (a >= 1) s1 += pz.x;
            if (a <= 1) s2 += pz.y;
        }
#pragma unroll
        for (int off = 1; off < 16; off <<= 1) {
            s1 += __shfl_xor(s1, off);
            s2 += __shfl_xor(s2, off);
            s3 += __shfl_xor(s3, off);
        }
        if (sl == 0) {
            float4 icv = *(const float4*)(invc4 + (size_t)v * 4);
            float zsum = pz4[(size_t)v * 4 + 3];
            float val = s1 * icv.x + s2 * icv.y + s3 * icv.z + zsum;
            outp[v] = 1.f / (1.f + expf(-val));
        }
    }
}

// ---------- launch ----------
extern "C" void kernel_launch(void* const* d_in, const int* in_sizes, int n_in,
                              void* d_out, int out_size, void* d_ws, size_t ws_size,
                              hipStream_t stream)
{
    const float* x    = (const float*)d_in[0];
    const int* ei     = (const int*)d_in[1];
    const int* attr   = (const int*)d_in[2];
    const float* Wspf = (const float*)d_in[3];
    const float* bspf = (const float*)d_in[4];
    const float* W011 = (const float*)d_in[5];
    const float* b011 = (const float*)d_in[6];
    const float* W012 = (const float*)d_in[7];
    const float* b012 = (const float*)d_in[8];
    const float* bn01 = (const float*)d_in[9];
    const float* eW1[3] = { (const float*)d_in[10], (const float*)d_in[15], (const float*)d_in[20] };
    const float* eb1[3] = { (const float*)d_in[11], (const float*)d_in[16], (const float*)d_in[21] };
    const float* eW2[3] = { (const float*)d_in[12], (const float*)d_in[17], (const float*)d_in[22] };
    const float* eb2[3] = { (const float*)d_in[13], (const float*)d_in[18], (const float*)d_in[23] };
    const float* bn1[3] = { (const float*)d_in[14], (const float*)d_in[19], (const float*)d_in[24] };
    const float* s21Wl = (const float*)d_in[25];
    const float* s21bl = (const float*)d_in[26];
    const float* s21Wr = (const float*)d_in[27];
    const float* bn21  = (const float*)d_in[28];
    const float* s3Wl[3] = { (const float*)d_in[29], (const float*)d_in[32], (const float*)d_in[35] };
    const float* s3bl[3] = { (const float*)d_in[30], (const float*)d_in[33], (const float*)d_in[36] };
    const float* s3Wr[3] = { (const float*)d_in[31], (const float*)d_in[34], (const float*)d_in[37] };

    char* ws = (char*)d_ws;
    unsigned short* Whl = (unsigned short*)(ws + OFF_WHL);
    float* WspP   = (float*)(ws + OFF_WSPP);
    float* bias01 = (float*)(ws + OFF_BIAS01);
    f16*   W1h    = (f16*)(ws + OFF_W1PQT);
    float* biasPQ = (float*)(ws + OFF_BIASPQ);
    f16*   Wsg16  = (f16*)(ws + OFF_WSAGET);
    float* bias21 = (float*)(ws + OFF_BIAS21);
    float* bnf    = (float*)(ws + OFF_BNF);
    f16*   W2h    = (f16*)(ws + OFF_W2BF);
    float* invc4  = (float*)(ws + OFF_INVC4);
    float* pz4    = (float*)(ws + OFF_PZ4);
    int*   rp     = (int*)(ws + OFF_RP);
    int*   parts  = (int*)(ws + OFF_PARTS);
    int*   deg    = (int*)(ws + OFF_DEG);
    unsigned int* cnt01 = (unsigned int*)(ws + OFF_CNT01);
    int*   ghead  = (int*)(ws + OFF_GHEAD);
    int*   sorted = (int*)(ws + OFF_SORT);
    unsigned int* ebuck = (unsigned int*)(ws + OFF_EBUCK);
    f16*   h16    = (f16*)(ws + OFF_H);
    f16*   Pi     = (f16*)(ws + OFF_PI);
    f16*   Qi     = (f16*)(ws + OFF_QI);
    f16*   y1i    = (f16*)(ws + OFF_Y1I);
    f16*   aggi   = (f16*)(ws + OFF_AGGI);   // overlays Pi (dead after edgeconv)

    hipMemsetAsync(ws + OFF_DEG, 0, 200064, stream);   // deg only (cnt01 fully written by bucketB)

    k_prep<<<689, 256, 0, stream>>>(
        Wspf, bspf, W011, b011, W012, b012, bn01,
        eW1[0], eb1[0], eb2[0], bn1[0],
        eW1[1], eb1[1], eb2[1], bn1[1],
        eW1[2], eb1[2], eb2[2], bn1[2],
        eW2[0], eW2[1], eW2[2],
        s21Wl, s21bl, s21Wr, bn21,
        Whl, WspP, bias01, W1h, biasPQ, Wsg16, bias21, bnf, W2h);

    k_hist<<<3907, 256, 0, stream>>>(ei + EE, deg);
    k_psum<<<NBK, 256, 0, stream>>>(deg, parts);
    k_pscan<<<1, 256, 0, stream>>>(parts, ghead);
    k_scanfix<<<NBK, 256, 0, stream>>>(deg, parts, rp);
    k_bucketA<<<245, 256, 0, stream>>>(ei, ei + EE, attr, ghead, ebuck);
    k_bucketB<<<NBK, 256, 0, stream>>>(rp, ebuck, sorted, cnt01);

    k_h<<<3125, 256, 0, stream>>>(x, Whl, WspP, bias01, h16);

    k_pq<<<782, 256, 0, stream>>>(h16, W1h, biasPQ, Pi, Qi);

    k_edgeconv_f<<<PW_EC / 4, 256, 0, stream>>>(rp, cnt01, sorted, Pi, Qi, W2h, bnf, y1i, invc4);
    k_agg_f<<<PW_AG / 4, 256, 0, stream>>>(rp, cnt01, sorted, y1i, invc4, aggi);

    k_sage1<<<782, 256, 0, stream>>>(aggi, y1i, Wsg16, bias21,
                                     s3Wl[0], s3bl[0], s3Wr[0],
                                     s3Wl[1], s3bl[1], s3Wr[1],
                                     s3Wl[2], s3bl[2], s3Wr[2], pz4);

    k_sage2_f<<<PW_AG / 4, 256, 0, stream>>>(rp, sorted, pz4, invc4, (float*)d_out);
}